// Round 1
// baseline (766.094 us; speedup 1.0000x reference)
//
#include <hip/hip_runtime.h>
#include <math.h>

// ---- problem constants ----
static constexpr int B_  = 4;
static constexpr int C_  = 64;
static constexpr int H_  = 96;
static constexpr int W_  = 320;
static constexpr int HW  = H_ * W_;          // 30720
static constexpr int RCH = 16;               // RC = C/4
static constexpr int D_  = 48;
static constexpr int NG  = 8;                // groupnorm groups
static constexpr int CPG = RCH / NG;         // 2 channels per group
static constexpr float EPS_ = 1e-5f;

__device__ __forceinline__ float elu1(float x) { return x > 0.f ? x : __expf(x) - 1.f; }
__device__ __forceinline__ float sigm(float x) { return 1.f / (1.f + __expf(-x)); }

// ---------- 1. 1x1 conv: left->qraw, right->kraw (no bias) ----------
__global__ __launch_bounds__(256) void k_conv_qk(
    const float* __restrict__ left, const float* __restrict__ right,
    const float* __restrict__ qw, const float* __restrict__ kw,
    float* __restrict__ qraw, float* __restrict__ kraw)
{
    __shared__ float swq[RCH * C_], swk[RCH * C_];
    for (int i = threadIdx.x; i < RCH * C_; i += 256) { swq[i] = qw[i]; swk[i] = kw[i]; }
    __syncthreads();
    int idx = blockIdx.x * 256 + threadIdx.x;      // exactly B_*HW threads
    int b = idx / HW, p = idx - b * HW;
    const float* lb = left  + (size_t)b * C_ * HW + p;
    const float* rb = right + (size_t)b * C_ * HW + p;
    float aq[RCH], ak[RCH];
#pragma unroll
    for (int r = 0; r < RCH; r++) { aq[r] = 0.f; ak[r] = 0.f; }
    for (int c = 0; c < C_; c++) {
        float lv = lb[(size_t)c * HW];
        float rv = rb[(size_t)c * HW];
#pragma unroll
        for (int r = 0; r < RCH; r++) {
            aq[r] += lv * swq[r * C_ + c];
            ak[r] += rv * swk[r * C_ + c];
        }
    }
#pragma unroll
    for (int r = 0; r < RCH; r++) {
        qraw[((size_t)b * RCH + r) * HW + p] = aq[r];
        kraw[((size_t)b * RCH + r) * HW + p] = ak[r];
    }
}

// ---------- 2. group-norm stats: one block per (b,g) ----------
__global__ __launch_bounds__(256) void k_gn_stats(const float* __restrict__ src, float* __restrict__ stats)
{
    int b = blockIdx.x / NG, g = blockIdx.x % NG;
    const float* base = src + ((size_t)b * RCH + g * CPG) * HW;
    float s = 0.f, ss = 0.f;
    for (int i = threadIdx.x; i < CPG * HW; i += 256) { float v = base[i]; s += v; ss += v * v; }
    __shared__ float rs[256], rq[256];
    rs[threadIdx.x] = s; rq[threadIdx.x] = ss; __syncthreads();
    for (int off = 128; off > 0; off >>= 1) {
        if (threadIdx.x < off) { rs[threadIdx.x] += rs[threadIdx.x + off]; rq[threadIdx.x] += rq[threadIdx.x + off]; }
        __syncthreads();
    }
    if (threadIdx.x == 0) {
        float inv = 1.f / (float)(CPG * HW);
        float m = rs[0] * inv;
        float var = rq[0] * inv - m * m;
        stats[blockIdx.x * 2 + 0] = m;
        stats[blockIdx.x * 2 + 1] = rsqrtf(var + EPS_);
    }
}

// ---------- 3. GN apply + elu, in place (for q) ----------
__global__ __launch_bounds__(256) void k_gn_apply(float* __restrict__ x, const float* __restrict__ stats,
    const float* __restrict__ gam, const float* __restrict__ bet)
{
    int idx = blockIdx.x * 256 + threadIdx.x;      // B_*RCH*HW threads
    int b = idx / (RCH * HW);
    int rc = (idx / HW) % RCH;
    int g = rc >> 1;
    float m = stats[(b * NG + g) * 2], is = stats[(b * NG + g) * 2 + 1];
    float v = (x[idx] - m) * is * gam[rc] + bet[rc];
    x[idx] = elu1(v);
}

// ---------- 4. km = mean over channels of elu(GN(kraw)) ----------
__global__ __launch_bounds__(256) void k_km(const float* __restrict__ kraw, const float* __restrict__ stats,
    const float* __restrict__ gam, const float* __restrict__ bet, float* __restrict__ km)
{
    int idx = blockIdx.x * 256 + threadIdx.x;      // B_*HW
    int b = idx / HW, p = idx - b * HW;
    float s = 0.f;
#pragma unroll
    for (int rc = 0; rc < RCH; rc++) {
        int g = rc >> 1;
        float m = stats[(b * NG + g) * 2], is = stats[(b * NG + g) * 2 + 1];
        float v = (kraw[((size_t)b * RCH + rc) * HW + p] - m) * is * gam[rc] + bet[rc];
        s += elu1(v);
    }
    km[idx] = s * (1.f / (float)RCH);
}

// ---------- 5. per-row mean over HW (used for gp and ymean) ----------
__global__ __launch_bounds__(256) void k_rowmean(const float* __restrict__ src, float* __restrict__ out)
{
    const float* base = src + (size_t)blockIdx.x * HW;
    float s = 0.f;
    for (int p = threadIdx.x; p < HW; p += 256) s += base[p];
    __shared__ float red[256];
    red[threadIdx.x] = s; __syncthreads();
    for (int off = 128; off > 0; off >>= 1) {
        if (threadIdx.x < off) red[threadIdx.x] += red[threadIdx.x + off];
        __syncthreads();
    }
    if (threadIdx.x == 0) out[blockIdx.x] = red[0] * (1.f / (float)HW);
}

// ---------- 6. gfeat MLP + fold into attn-hidden bias: gbias[b,o] ----------
__global__ __launch_bounds__(64) void k_gfeat(const float* __restrict__ gp,
    const float* __restrict__ gaw1, const float* __restrict__ gab1,
    const float* __restrict__ gaw2, const float* __restrict__ gab2,
    const float* __restrict__ afw1, const float* __restrict__ afb1,
    float* __restrict__ gbias)
{
    __shared__ float g1[B_ * 8], gf[B_ * RCH];
    int t = threadIdx.x;
    if (t < B_ * 8) {
        int b = t >> 3, o = t & 7;
        float a = gab1[o];
        for (int i = 0; i < RCH; i++) a += gaw1[o * RCH + i] * gp[b * RCH + i];
        g1[b * 8 + o] = elu1(a);
    }
    __syncthreads();
    {
        int b = t >> 4, o = t & 15;
        float a = gab2[o];
        for (int i = 0; i < 8; i++) a += gaw2[o * 8 + i] * g1[b * 8 + i];
        gf[t] = a;
    }
    __syncthreads();
    {
        int b = t >> 4, o = t & 15;
        float a = afb1[o];
        for (int i = 0; i < RCH; i++) a += afw1[o * 2 * RCH + i] * gf[b * RCH + i];
        gbias[t] = a;
    }
}

// ---------- 7. 3x3 conv q -> lraw (zero pad, bias) ----------
__global__ __launch_bounds__(256) void k_conv_la(const float* __restrict__ q,
    const float* __restrict__ law, const float* __restrict__ lab, float* __restrict__ lraw)
{
    __shared__ float wl[RCH * RCH * 9];   // 2304
    for (int i = threadIdx.x; i < RCH * RCH * 9; i += 256) wl[i] = law[i];
    __syncthreads();
    int idx = blockIdx.x * 256 + threadIdx.x;      // B_*HW
    int b = idx / HW, p = idx - b * HW;
    int h = p / W_, w = p - h * W_;
    float acc[RCH];
#pragma unroll
    for (int co = 0; co < RCH; co++) acc[co] = lab[co];
    for (int ci = 0; ci < RCH; ci++) {
        const float* qb = q + ((size_t)b * RCH + ci) * HW;
#pragma unroll
        for (int kh = 0; kh < 3; kh++) {
            int hh = h + kh - 1;
            if (hh < 0 || hh >= H_) continue;
            float a0 = (w - 1 >= 0) ? qb[hh * W_ + w - 1] : 0.f;
            float a1 = qb[hh * W_ + w];
            float a2 = (w + 1 < W_) ? qb[hh * W_ + w + 1] : 0.f;
#pragma unroll
            for (int co = 0; co < RCH; co++) {
                const float* wp = &wl[(co * RCH + ci) * 9 + kh * 3];
                acc[co] += a0 * wp[0] + a1 * wp[1] + a2 * wp[2];
            }
        }
    }
#pragma unroll
    for (int co = 0; co < RCH; co++) lraw[((size_t)b * RCH + co) * HW + p] = acc[co];
}

// ---------- 8. fused: GN(lraw)+elu -> attn MLP -> sigmoid; warp km; vol ----------
__global__ __launch_bounds__(256) void k_vol(const float* __restrict__ lraw,
    const float* __restrict__ stats, const float* __restrict__ lg, const float* __restrict__ lb,
    const float* __restrict__ gbias, const float* __restrict__ afw1,
    const float* __restrict__ afw2, const float* __restrict__ afb2,
    const float* __restrict__ km, const float* __restrict__ directs, float* __restrict__ vol)
{
    __shared__ float w1[RCH * 2 * RCH];   // 512
    __shared__ float w2[D_ * RCH];        // 768
    __shared__ float b2[D_];
    for (int i = threadIdx.x; i < RCH * 2 * RCH; i += 256) w1[i] = afw1[i];
    for (int i = threadIdx.x; i < D_ * RCH; i += 256) w2[i] = afw2[i];
    if (threadIdx.x < D_) b2[threadIdx.x] = afb2[threadIdx.x];
    __syncthreads();
    int idx = blockIdx.x * 256 + threadIdx.x;      // B_*HW
    int b = idx / HW, p = idx - b * HW;
    int h = p / W_, w = p - h * W_;
    float lf[RCH];
#pragma unroll
    for (int rc = 0; rc < RCH; rc++) {
        int g = rc >> 1;
        float m = stats[(b * NG + g) * 2], is = stats[(b * NG + g) * 2 + 1];
        lf[rc] = elu1((lraw[((size_t)b * RCH + rc) * HW + p] - m) * is * lg[rc] + lb[rc]);
    }
    float hid[RCH];
#pragma unroll
    for (int o = 0; o < RCH; o++) {
        float a = gbias[b * RCH + o];
#pragma unroll
        for (int i = 0; i < RCH; i++) a += w1[o * 2 * RCH + RCH + i] * lf[i];
        hid[o] = elu1(a);
    }
    const float* kmrow = km + (size_t)b * HW + h * W_;
    float dir = directs[b];
    for (int d = 0; d < D_; d++) {
        float a = b2[d];
#pragma unroll
        for (int o = 0; o < RCH; o++) a += w2[d * RCH + o] * hid[o];
        float s = sigm(a);
        float shift = ((float)d / 160.f) * dir * (float)(W_ - 1);
        float pos = (float)w + shift;
        float x0 = floorf(pos);
        float f = pos - x0;
        float c0 = fminf(fmaxf(x0, 0.f), (float)(W_ - 1));
        float c1 = fminf(fmaxf(x0 + 1.f, 0.f), (float)(W_ - 1));
        int i0 = (int)c0, i1 = (int)c1;
        float wv = kmrow[i0] * (1.f - f) + kmrow[i1] * f;
        vol[((size_t)(b * D_ + d)) * HW + p] = wv * s;
    }
}

// ---------- 9. depthwise 3x3 + elu ----------
__global__ __launch_bounds__(256) void k_dw(const float* __restrict__ vol,
    const float* __restrict__ wgt, const float* __restrict__ bias, float* __restrict__ dwout)
{
    int idx = blockIdx.x * 256 + threadIdx.x;      // B_*D_*HW
    int p = idx % HW;
    int d = (idx / HW) % D_;
    int b = idx / (D_ * HW);
    int h = p / W_, w = p - h * W_;
    const float* vb = vol + ((size_t)(b * D_ + d)) * HW;
    float acc = bias[d];
#pragma unroll
    for (int kh = 0; kh < 3; kh++) {
        int hh = h + kh - 1;
        if (hh < 0 || hh >= H_) continue;
#pragma unroll
        for (int kw2 = 0; kw2 < 3; kw2++) {
            int ww = w + kw2 - 1;
            if (ww < 0 || ww >= W_) continue;
            acc += vb[hh * W_ + ww] * wgt[d * 9 + kh * 3 + kw2];
        }
    }
    dwout[idx] = elu1(acc);
}

// ---------- 10. 1x1 48->48 + softmax over channels -> norm_cost ----------
__global__ __launch_bounds__(256) void k_rpw(const float* __restrict__ dwin,
    const float* __restrict__ wgt, const float* __restrict__ bias, float* __restrict__ ncost)
{
    __shared__ float wr[D_ * D_];   // 2304
    for (int i = threadIdx.x; i < D_ * D_; i += 256) wr[i] = wgt[i];
    __syncthreads();
    int idx = blockIdx.x * 256 + threadIdx.x;      // B_*HW
    int b = idx / HW, p = idx - b * HW;
    float v[D_];
#pragma unroll
    for (int i = 0; i < D_; i++) v[i] = dwin[((size_t)(b * D_ + i)) * HW + p];
    float cst[D_];
    float mx = -1e30f;
    for (int d = 0; d < D_; d++) {
        float a = bias[d];
#pragma unroll
        for (int i = 0; i < D_; i++) a += wr[d * D_ + i] * v[i];
        cst[d] = a; mx = fmaxf(mx, a);
    }
    float s = 0.f;
#pragma unroll
    for (int d = 0; d < D_; d++) { float e = __expf(cst[d] - mx); cst[d] = e; s += e; }
    float inv = 1.f / s;
#pragma unroll
    for (int d = 0; d < D_; d++) ncost[((size_t)(b * D_ + d)) * HW + p] = cst[d] * inv;
}

// ---------- 11. fused 3x3 conv, 112->64, reflect pad ----------
static constexpr int TW = 40;
static constexpr int TILE_W = TW + 2;   // 42
static constexpr int CIN = C_ + D_;     // 112
__global__ __launch_bounds__(256) void k_fused(
    const float* __restrict__ left, const float* __restrict__ ncost,
    const float* __restrict__ fw, const float* __restrict__ fb, float* __restrict__ fused)
{
    __shared__ float tile[CIN * 3 * TILE_W];   // 14112 floats = 56.4 KB
    int h = blockIdx.y, b = blockIdx.z;
    int w0 = blockIdx.x * TW;
    // vectorized interior staging (x = 1..40)
    for (int i = threadIdx.x; i < 336 * 10; i += 256) {
        int row = i / 10, seg = i - row * 10;   // row = ci*3 + r
        int ci = row / 3, r = row - ci * 3;
        int hh = h - 1 + r; hh = hh < 0 ? -hh : (hh >= H_ ? 2 * H_ - 2 - hh : hh);
        const float* src = (ci < C_) ? (left + ((size_t)(b * C_ + ci)) * HW)
                                     : (ncost + ((size_t)(b * D_ + (ci - C_))) * HW);
        const float4 vv = *reinterpret_cast<const float4*>(src + hh * W_ + w0 + seg * 4);
        float* dst = &tile[row * TILE_W + 1 + seg * 4];
        dst[0] = vv.x; dst[1] = vv.y; dst[2] = vv.z; dst[3] = vv.w;
    }
    // edges x=0 and x=41 (reflect in w)
    for (int row = threadIdx.x; row < 336; row += 256) {
        int ci = row / 3, r = row - ci * 3;
        int hh = h - 1 + r; hh = hh < 0 ? -hh : (hh >= H_ ? 2 * H_ - 2 - hh : hh);
        const float* src = (ci < C_) ? (left + ((size_t)(b * C_ + ci)) * HW)
                                     : (ncost + ((size_t)(b * D_ + (ci - C_))) * HW);
        int wl2 = w0 - 1; if (wl2 < 0) wl2 = 1;
        int wr2 = w0 + TW; if (wr2 >= W_) wr2 = 2 * W_ - 2 - wr2;
        tile[row * TILE_W + 0] = src[hh * W_ + wl2];
        tile[row * TILE_W + TILE_W - 1] = src[hh * W_ + wr2];
    }
    __syncthreads();
    int pg = threadIdx.x & 7;     // pixel group: pixels pg*5 .. pg*5+4
    int cog = threadIdx.x >> 3;   // 0..31
    int co0 = cog * 2;
    float acc[2][5];
#pragma unroll
    for (int j = 0; j < 2; j++) {
        float bj = fb[co0 + j];
#pragma unroll
        for (int x = 0; x < 5; x++) acc[j][x] = bj;
    }
    for (int ci = 0; ci < CIN; ++ci) {
#pragma unroll
        for (int r = 0; r < 3; ++r) {
            const float* trow = &tile[(ci * 3 + r) * TILE_W + pg * 5];
            float in7[7];
#pragma unroll
            for (int k = 0; k < 7; k++) in7[k] = trow[k];
#pragma unroll
            for (int j = 0; j < 2; j++) {
                const float* wp = fw + (((size_t)(co0 + j)) * CIN + ci) * 9 + r * 3;
                float w0v = wp[0], w1v = wp[1], w2v = wp[2];
#pragma unroll
                for (int x = 0; x < 5; x++) acc[j][x] += in7[x] * w0v + in7[x + 1] * w1v + in7[x + 2] * w2v;
            }
        }
    }
    int wb = w0 + pg * 5;
#pragma unroll
    for (int j = 0; j < 2; j++) {
        float* ob = fused + ((size_t)(b * C_ + co0 + j)) * HW + h * W_ + wb;
#pragma unroll
        for (int x = 0; x < 5; x++) ob[x] = acc[j][x];
    }
}

// ---------- 12. SE MLP ----------
__global__ __launch_bounds__(256) void k_se(const float* __restrict__ ymean,
    const float* __restrict__ w1, const float* __restrict__ w2, float* __restrict__ scale)
{
    __shared__ float h4[B_ * 4];
    int t = threadIdx.x;
    if (t < B_ * 4) {
        int b = t >> 2, o = t & 3;
        float a = 0.f;
        for (int c = 0; c < C_; c++) a += w1[o * C_ + c] * ymean[b * C_ + c];
        h4[b * 4 + o] = fmaxf(a, 0.f);
    }
    __syncthreads();
    {
        int b = t >> 6, c = t & 63;
        float a = 0.f;
        for (int o = 0; o < 4; o++) a += w2[c * 4 + o] * h4[b * 4 + o];
        scale[t] = sigm(a);
    }
}

// ---------- 13. final: x = elu(fused * scale) ----------
__global__ __launch_bounds__(256) void k_final(const float* __restrict__ fused,
    const float* __restrict__ scale, float* __restrict__ out)
{
    int idx = blockIdx.x * 256 + threadIdx.x;      // B_*C_*HW
    int bc = idx / HW;
    out[idx] = elu1(fused[idx] * scale[bc]);
}

extern "C" void kernel_launch(void* const* d_in, const int* in_sizes, int n_in,
                              void* d_out, int out_size, void* d_ws, size_t ws_size,
                              hipStream_t stream)
{
    const float* left   = (const float*)d_in[0];
    const float* right  = (const float*)d_in[1];
    const float* directs= (const float*)d_in[2];
    const float* qw     = (const float*)d_in[3];
    const float* q_g    = (const float*)d_in[4];
    const float* q_b    = (const float*)d_in[5];
    const float* kw     = (const float*)d_in[6];
    const float* k_g    = (const float*)d_in[7];
    const float* k_b    = (const float*)d_in[8];
    const float* gaw1   = (const float*)d_in[9];
    const float* gab1   = (const float*)d_in[10];
    const float* gaw2   = (const float*)d_in[11];
    const float* gab2   = (const float*)d_in[12];
    const float* law    = (const float*)d_in[13];
    const float* lab    = (const float*)d_in[14];
    const float* lag    = (const float*)d_in[15];
    const float* labb   = (const float*)d_in[16];
    const float* afw1   = (const float*)d_in[17];
    const float* afb1   = (const float*)d_in[18];
    const float* afw2   = (const float*)d_in[19];
    const float* afb2   = (const float*)d_in[20];
    const float* rdww   = (const float*)d_in[21];
    const float* rdwb   = (const float*)d_in[22];
    const float* rpww   = (const float*)d_in[23];
    const float* rpwb   = (const float*)d_in[24];
    const float* fuw    = (const float*)d_in[25];
    const float* fub    = (const float*)d_in[26];
    const float* sew1   = (const float*)d_in[27];
    const float* sew2   = (const float*)d_in[28];

    // workspace layout (floats). Peak use: 15,852,544 floats = 63.4 MB.
    float* ws    = (float*)d_ws;
    float* qraw  = ws + 0;          // B*RC*HW = 1,966,080 ; becomes q in-place
    float* kraw  = ws + 1966080;    // 1,966,080 ; reused as lraw after km
    float* km    = ws + 3932160;    // B*HW = 122,880
    float* vol   = ws + 4055040;    // B*D*HW = 5,898,240
    float* dwb   = ws + 9953280;    // B*D*HW = 5,898,240
    float* smal  = ws + 15851520;   // 1024 floats of stats/small tensors
    float* fused = ws + 0;          // B*C*HW = 7,864,320 ; overlaps dead qraw/kraw/km/vol (safe: written after their last reads)
    float* lraw  = kraw;

    float* stQ   = smal + 0;    // 64: (b,g) mean/invstd
    float* stK   = smal + 64;
    float* stL   = smal + 128;
    float* gp    = smal + 192;  // 64
    float* gbias = smal + 256;  // 64
    float* ymean = smal + 320;  // 256
    float* scal  = smal + 576;  // 256

    float* xout  = (float*)d_out;            // 7,864,320
    float* ncost = xout + 7864320;           // 5,898,240

    k_conv_qk<<<480, 256, 0, stream>>>(left, right, qw, kw, qraw, kraw);
    k_gn_stats<<<32, 256, 0, stream>>>(qraw, stQ);
    k_gn_stats<<<32, 256, 0, stream>>>(kraw, stK);
    k_gn_apply<<<7680, 256, 0, stream>>>(qraw, stQ, q_g, q_b);
    k_km<<<480, 256, 0, stream>>>(kraw, stK, k_g, k_b, km);
    k_rowmean<<<64, 256, 0, stream>>>(qraw, gp);
    k_gfeat<<<1, 64, 0, stream>>>(gp, gaw1, gab1, gaw2, gab2, afw1, afb1, gbias);
    k_conv_la<<<480, 256, 0, stream>>>(qraw, law, lab, lraw);
    k_gn_stats<<<32, 256, 0, stream>>>(lraw, stL);
    k_vol<<<480, 256, 0, stream>>>(lraw, stL, lag, labb, gbias, afw1, afw2, afb2, km, directs, vol);
    k_dw<<<23040, 256, 0, stream>>>(vol, rdww, rdwb, dwb);
    k_rpw<<<480, 256, 0, stream>>>(dwb, rpww, rpwb, ncost);
    k_fused<<<dim3(8, 96, 4), 256, 0, stream>>>(left, ncost, fuw, fub, fused);
    k_rowmean<<<256, 256, 0, stream>>>(fused, ymean);
    k_se<<<1, 256, 0, stream>>>(ymean, sew1, sew2, scal);
    k_final<<<30720, 256, 0, stream>>>(fused, scal, xout);
}

// Round 2
// 526.711 us; speedup vs baseline: 1.4545x; 1.4545x over previous
//
#include <hip/hip_runtime.h>
#include <math.h>

// ---- problem constants ----
static constexpr int B_  = 4;
static constexpr int C_  = 64;
static constexpr int H_  = 96;
static constexpr int W_  = 320;
static constexpr int HW  = H_ * W_;          // 30720
static constexpr int RCH = 16;               // RC = C/4
static constexpr int D_  = 48;
static constexpr int NG  = 8;                // groupnorm groups
static constexpr int CPG = RCH / NG;         // 2 channels per group
static constexpr float EPS_ = 1e-5f;

typedef __attribute__((ext_vector_type(8))) short short8;
typedef __attribute__((ext_vector_type(4))) float f32x4;

__device__ __forceinline__ float elu1(float x) { return x > 0.f ? x : __expf(x) - 1.f; }
__device__ __forceinline__ float sigm(float x) { return 1.f / (1.f + __expf(-x)); }
__device__ __forceinline__ unsigned bf16rne(float f) {
    unsigned u = __builtin_bit_cast(unsigned, f);
    u += 0x7fffu + ((u >> 16) & 1u);
    return u >> 16;
}

// ---------- 1. 1x1 conv: left->qraw, right->kraw (no bias) ----------
__global__ __launch_bounds__(256) void k_conv_qk(
    const float* __restrict__ left, const float* __restrict__ right,
    const float* __restrict__ qw, const float* __restrict__ kw,
    float* __restrict__ qraw, float* __restrict__ kraw)
{
    __shared__ float swq[RCH * C_], swk[RCH * C_];
    for (int i = threadIdx.x; i < RCH * C_; i += 256) { swq[i] = qw[i]; swk[i] = kw[i]; }
    __syncthreads();
    int idx = blockIdx.x * 256 + threadIdx.x;      // exactly B_*HW threads
    int b = idx / HW, p = idx - b * HW;
    const float* lb = left  + (size_t)b * C_ * HW + p;
    const float* rb = right + (size_t)b * C_ * HW + p;
    float aq[RCH], ak[RCH];
#pragma unroll
    for (int r = 0; r < RCH; r++) { aq[r] = 0.f; ak[r] = 0.f; }
    for (int c = 0; c < C_; c++) {
        float lv = lb[(size_t)c * HW];
        float rv = rb[(size_t)c * HW];
#pragma unroll
        for (int r = 0; r < RCH; r++) {
            aq[r] += lv * swq[r * C_ + c];
            ak[r] += rv * swk[r * C_ + c];
        }
    }
#pragma unroll
    for (int r = 0; r < RCH; r++) {
        qraw[((size_t)b * RCH + r) * HW + p] = aq[r];
        kraw[((size_t)b * RCH + r) * HW + p] = ak[r];
    }
}

// ---------- 2. group-norm stats: one block per (b,g) ----------
__global__ __launch_bounds__(256) void k_gn_stats(const float* __restrict__ src, float* __restrict__ stats)
{
    int b = blockIdx.x / NG, g = blockIdx.x % NG;
    const float* base = src + ((size_t)b * RCH + g * CPG) * HW;
    float s = 0.f, ss = 0.f;
    for (int i = threadIdx.x; i < CPG * HW; i += 256) { float v = base[i]; s += v; ss += v * v; }
    __shared__ float rs[256], rq[256];
    rs[threadIdx.x] = s; rq[threadIdx.x] = ss; __syncthreads();
    for (int off = 128; off > 0; off >>= 1) {
        if (threadIdx.x < off) { rs[threadIdx.x] += rs[threadIdx.x + off]; rq[threadIdx.x] += rq[threadIdx.x + off]; }
        __syncthreads();
    }
    if (threadIdx.x == 0) {
        float inv = 1.f / (float)(CPG * HW);
        float m = rs[0] * inv;
        float var = rq[0] * inv - m * m;
        stats[blockIdx.x * 2 + 0] = m;
        stats[blockIdx.x * 2 + 1] = rsqrtf(var + EPS_);
    }
}

// ---------- 3. GN apply + elu, in place (for q) ----------
__global__ __launch_bounds__(256) void k_gn_apply(float* __restrict__ x, const float* __restrict__ stats,
    const float* __restrict__ gam, const float* __restrict__ bet)
{
    int idx = blockIdx.x * 256 + threadIdx.x;      // B_*RCH*HW threads
    int b = idx / (RCH * HW);
    int rc = (idx / HW) % RCH;
    int g = rc >> 1;
    float m = stats[(b * NG + g) * 2], is = stats[(b * NG + g) * 2 + 1];
    float v = (x[idx] - m) * is * gam[rc] + bet[rc];
    x[idx] = elu1(v);
}

// ---------- 4. km = mean over channels of elu(GN(kraw)) ----------
__global__ __launch_bounds__(256) void k_km(const float* __restrict__ kraw, const float* __restrict__ stats,
    const float* __restrict__ gam, const float* __restrict__ bet, float* __restrict__ km)
{
    int idx = blockIdx.x * 256 + threadIdx.x;      // B_*HW
    int b = idx / HW, p = idx - b * HW;
    float s = 0.f;
#pragma unroll
    for (int rc = 0; rc < RCH; rc++) {
        int g = rc >> 1;
        float m = stats[(b * NG + g) * 2], is = stats[(b * NG + g) * 2 + 1];
        float v = (kraw[((size_t)b * RCH + rc) * HW + p] - m) * is * gam[rc] + bet[rc];
        s += elu1(v);
    }
    km[idx] = s * (1.f / (float)RCH);
}

// ---------- 5. per-row mean over HW (used for gp and ymean) ----------
__global__ __launch_bounds__(256) void k_rowmean(const float* __restrict__ src, float* __restrict__ out)
{
    const float* base = src + (size_t)blockIdx.x * HW;
    float s = 0.f;
    for (int p = threadIdx.x; p < HW; p += 256) s += base[p];
    __shared__ float red[256];
    red[threadIdx.x] = s; __syncthreads();
    for (int off = 128; off > 0; off >>= 1) {
        if (threadIdx.x < off) red[threadIdx.x] += red[threadIdx.x + off];
        __syncthreads();
    }
    if (threadIdx.x == 0) out[blockIdx.x] = red[0] * (1.f / (float)HW);
}

// ---------- 6. gfeat MLP + fold into attn-hidden bias: gbias[b,o] ----------
__global__ __launch_bounds__(64) void k_gfeat(const float* __restrict__ gp,
    const float* __restrict__ gaw1, const float* __restrict__ gab1,
    const float* __restrict__ gaw2, const float* __restrict__ gab2,
    const float* __restrict__ afw1, const float* __restrict__ afb1,
    float* __restrict__ gbias)
{
    __shared__ float g1[B_ * 8], gf[B_ * RCH];
    int t = threadIdx.x;
    if (t < B_ * 8) {
        int b = t >> 3, o = t & 7;
        float a = gab1[o];
        for (int i = 0; i < RCH; i++) a += gaw1[o * RCH + i] * gp[b * RCH + i];
        g1[b * 8 + o] = elu1(a);
    }
    __syncthreads();
    {
        int b = t >> 4, o = t & 15;
        float a = gab2[o];
        for (int i = 0; i < 8; i++) a += gaw2[o * 8 + i] * g1[b * 8 + i];
        gf[t] = a;
    }
    __syncthreads();
    {
        int b = t >> 4, o = t & 15;
        float a = afb1[o];
        for (int i = 0; i < RCH; i++) a += afw1[o * 2 * RCH + i] * gf[b * RCH + i];
        gbias[t] = a;
    }
}

// ---------- 7. 3x3 conv q -> lraw (zero pad, bias) ----------
__global__ __launch_bounds__(256) void k_conv_la(const float* __restrict__ q,
    const float* __restrict__ law, const float* __restrict__ lab, float* __restrict__ lraw)
{
    __shared__ float wl[RCH * RCH * 9];   // 2304
    for (int i = threadIdx.x; i < RCH * RCH * 9; i += 256) wl[i] = law[i];
    __syncthreads();
    int idx = blockIdx.x * 256 + threadIdx.x;      // B_*HW
    int b = idx / HW, p = idx - b * HW;
    int h = p / W_, w = p - h * W_;
    float acc[RCH];
#pragma unroll
    for (int co = 0; co < RCH; co++) acc[co] = lab[co];
    for (int ci = 0; ci < RCH; ci++) {
        const float* qb = q + ((size_t)b * RCH + ci) * HW;
#pragma unroll
        for (int kh = 0; kh < 3; kh++) {
            int hh = h + kh - 1;
            if (hh < 0 || hh >= H_) continue;
            float a0 = (w - 1 >= 0) ? qb[hh * W_ + w - 1] : 0.f;
            float a1 = qb[hh * W_ + w];
            float a2 = (w + 1 < W_) ? qb[hh * W_ + w + 1] : 0.f;
#pragma unroll
            for (int co = 0; co < RCH; co++) {
                const float* wp = &wl[(co * RCH + ci) * 9 + kh * 3];
                acc[co] += a0 * wp[0] + a1 * wp[1] + a2 * wp[2];
            }
        }
    }
#pragma unroll
    for (int co = 0; co < RCH; co++) lraw[((size_t)b * RCH + co) * HW + p] = acc[co];
}

// ---------- 8. fused: GN(lraw)+elu -> attn MLP -> sigmoid; warp km; vol ----------
__global__ __launch_bounds__(256) void k_vol(const float* __restrict__ lraw,
    const float* __restrict__ stats, const float* __restrict__ lg, const float* __restrict__ lb,
    const float* __restrict__ gbias, const float* __restrict__ afw1,
    const float* __restrict__ afw2, const float* __restrict__ afb2,
    const float* __restrict__ km, const float* __restrict__ directs, float* __restrict__ vol)
{
    __shared__ float w1[RCH * 2 * RCH];   // 512
    __shared__ float w2[D_ * RCH];        // 768
    __shared__ float b2[D_];
    for (int i = threadIdx.x; i < RCH * 2 * RCH; i += 256) w1[i] = afw1[i];
    for (int i = threadIdx.x; i < D_ * RCH; i += 256) w2[i] = afw2[i];
    if (threadIdx.x < D_) b2[threadIdx.x] = afb2[threadIdx.x];
    __syncthreads();
    int idx = blockIdx.x * 256 + threadIdx.x;      // B_*HW
    int b = idx / HW, p = idx - b * HW;
    int h = p / W_, w = p - h * W_;
    float lf[RCH];
#pragma unroll
    for (int rc = 0; rc < RCH; rc++) {
        int g = rc >> 1;
        float m = stats[(b * NG + g) * 2], is = stats[(b * NG + g) * 2 + 1];
        lf[rc] = elu1((lraw[((size_t)b * RCH + rc) * HW + p] - m) * is * lg[rc] + lb[rc]);
    }
    float hid[RCH];
#pragma unroll
    for (int o = 0; o < RCH; o++) {
        float a = gbias[b * RCH + o];
#pragma unroll
        for (int i = 0; i < RCH; i++) a += w1[o * 2 * RCH + RCH + i] * lf[i];
        hid[o] = elu1(a);
    }
    const float* kmrow = km + (size_t)b * HW + h * W_;
    float dir = directs[b];
    for (int d = 0; d < D_; d++) {
        float a = b2[d];
#pragma unroll
        for (int o = 0; o < RCH; o++) a += w2[d * RCH + o] * hid[o];
        float s = sigm(a);
        float shift = ((float)d / 160.f) * dir * (float)(W_ - 1);
        float pos = (float)w + shift;
        float x0 = floorf(pos);
        float f = pos - x0;
        float c0 = fminf(fmaxf(x0, 0.f), (float)(W_ - 1));
        float c1 = fminf(fmaxf(x0 + 1.f, 0.f), (float)(W_ - 1));
        int i0 = (int)c0, i1 = (int)c1;
        float wv = kmrow[i0] * (1.f - f) + kmrow[i1] * f;
        vol[((size_t)(b * D_ + d)) * HW + p] = wv * s;
    }
}

// ---------- 9. depthwise 3x3 + elu ----------
__global__ __launch_bounds__(256) void k_dw(const float* __restrict__ vol,
    const float* __restrict__ wgt, const float* __restrict__ bias, float* __restrict__ dwout)
{
    int idx = blockIdx.x * 256 + threadIdx.x;      // B_*D_*HW
    int p = idx % HW;
    int d = (idx / HW) % D_;
    int b = idx / (D_ * HW);
    int h = p / W_, w = p - h * W_;
    const float* vb = vol + ((size_t)(b * D_ + d)) * HW;
    float acc = bias[d];
#pragma unroll
    for (int kh = 0; kh < 3; kh++) {
        int hh = h + kh - 1;
        if (hh < 0 || hh >= H_) continue;
#pragma unroll
        for (int kw2 = 0; kw2 < 3; kw2++) {
            int ww = w + kw2 - 1;
            if (ww < 0 || ww >= W_) continue;
            acc += vb[hh * W_ + ww] * wgt[d * 9 + kh * 3 + kw2];
        }
    }
    dwout[idx] = elu1(acc);
}

// ---------- 10. 1x1 48->48 + softmax over channels -> norm_cost ----------
__global__ __launch_bounds__(256) void k_rpw(const float* __restrict__ dwin,
    const float* __restrict__ wgt, const float* __restrict__ bias, float* __restrict__ ncost)
{
    __shared__ float wr[D_ * D_];   // 2304
    for (int i = threadIdx.x; i < D_ * D_; i += 256) wr[i] = wgt[i];
    __syncthreads();
    int idx = blockIdx.x * 256 + threadIdx.x;      // B_*HW
    int b = idx / HW, p = idx - b * HW;
    float v[D_];
#pragma unroll
    for (int i = 0; i < D_; i++) v[i] = dwin[((size_t)(b * D_ + i)) * HW + p];
    float cst[D_];
    float mx = -1e30f;
    for (int d = 0; d < D_; d++) {
        float a = bias[d];
#pragma unroll
        for (int i = 0; i < D_; i++) a += wr[d * D_ + i] * v[i];
        cst[d] = a; mx = fmaxf(mx, a);
    }
    float s = 0.f;
#pragma unroll
    for (int d = 0; d < D_; d++) { float e = __expf(cst[d] - mx); cst[d] = e; s += e; }
    float inv = 1.f / s;
#pragma unroll
    for (int d = 0; d < D_; d++) ncost[((size_t)(b * D_ + d)) * HW + p] = cst[d] * inv;
}

// ---------- 11a. weight prepack for MFMA fused conv ----------
// wpack[step(36)][ct(4)][lane(64)][j(8)] bf16, step = (kh*3+kw)*4 + kblk
// B[k][n]: k = kblk*32 + (lane>>4)*8 + j (ci, 128-padded), n = ct*16 + (lane&15) (co)
__global__ __launch_bounds__(256) void k_wpack(const float* __restrict__ fw, unsigned short* __restrict__ wpack)
{
    int bi = blockIdx.x;           // 0..35
    int tap = bi >> 2, kblk = bi & 3;
    int kh = tap / 3, kw2 = tap % 3;
    int t = threadIdx.x;
    int ct = t >> 6, l = t & 63;
    int co = ct * 16 + (l & 15);
    int ci0 = kblk * 32 + ((l >> 4) & 3) * 8;
    unsigned short v[8];
#pragma unroll
    for (int j = 0; j < 8; j++) {
        int ci = ci0 + j;
        float f = (ci < 112) ? fw[((size_t)(co * 112 + ci)) * 9 + kh * 3 + kw2] : 0.f;
        v[j] = (unsigned short)bf16rne(f);
    }
    *reinterpret_cast<short8*>(wpack + ((size_t)bi * 256 + t) * 8) = *reinterpret_cast<short8*>(v);
}

// ---------- 11b. fused 3x3 conv 112->64, reflect pad, bf16 MFMA implicit GEMM ----------
// Block: 2 output rows x 64 px x 64 co. 4 waves: wave = (row, co-half).
// A-LDS: 4 input rows x 66 px x 120 ci bf16 (240B stride, zero pad ci 112..119;
//        kblk3 hi-granule overread multiplies zero B -> harmless).
static constexpr int LROWB  = 240;           // bytes per px (120 bf16)
static constexpr int LPLANB = 66 * LROWB;    // 15840 bytes per input row
__global__ __launch_bounds__(256, 1) void k_fused_mfma(
    const float* __restrict__ left, const float* __restrict__ ncost,
    const unsigned short* __restrict__ wpack, const float* __restrict__ fb,
    float* __restrict__ fused)
{
    __shared__ __align__(16) unsigned int Atile4[15844];   // 63376 B (incl 16B overread pad)
    int bb = blockIdx.z;
    int h0 = blockIdx.y * 2;
    int w0 = blockIdx.x * 64;
    int tid = threadIdx.x;

    // ---- zero the ci pad (dwords 56..59 of each px row) ----
    for (int i = tid; i < 4 * 66 * 4; i += 256) {
        int row = i / 264, rem = i % 264;
        int px = rem >> 2, z = rem & 3;
        Atile4[row * 3960 + px * 60 + 56 + z] = 0u;
    }
    // ---- stage A: 4 rows x 66 px x 112 ci (fp32 -> bf16 pairs) ----
    // unit u = ((row*5 + chunk)*56 + cp); 16-lane group per unit; px = chunk*16 + lane_lo
    for (int u = (tid >> 4); u < 1120; u += 16) {
        int i = tid & 15;
        int cp = u % 56;
        int rc = u / 56;
        int chunk = rc % 5, row = rc / 5;
        int px = chunk * 16 + i;
        if (px < 66) {
            int hh = h0 - 1 + row;
            hh = hh < 0 ? -hh : (hh >= H_ ? 2 * H_ - 2 - hh : hh);
            int w = w0 - 1 + px;
            w = w < 0 ? -w : (w >= W_ ? 2 * W_ - 2 - w : w);
            int ci = cp * 2;
            const float* s0 = (ci < C_) ? (left + ((size_t)(bb * C_ + ci)) * HW)
                                        : (ncost + ((size_t)(bb * D_ + (ci - C_))) * HW);
            float f0 = s0[hh * W_ + w];
            float f1 = s0[HW + hh * W_ + w];
            Atile4[row * 3960 + px * 60 + cp] = bf16rne(f0) | (bf16rne(f1) << 16);
        }
    }
    __syncthreads();

    int wid = tid >> 6;          // wave id
    int row = wid >> 1;          // output row within block (0..1)
    int ch  = wid & 1;           // co half (0..1)
    int l   = tid & 63;
    int li  = l & 15, lg = l >> 4;

    const short8* __restrict__ wp8 = reinterpret_cast<const short8*>(wpack);

    f32x4 acc[4][2];
    float bv0 = fb[(ch * 2 + 0) * 16 + li];
    float bv1 = fb[(ch * 2 + 1) * 16 + li];
#pragma unroll
    for (int pt = 0; pt < 4; pt++) {
        acc[pt][0] = (f32x4){bv0, bv0, bv0, bv0};
        acc[pt][1] = (f32x4){bv1, bv1, bv1, bv1};
    }

    const char* Abase = (const char*)Atile4;
#pragma unroll
    for (int kh = 0; kh < 3; kh++) {
#pragma unroll
        for (int kw2 = 0; kw2 < 3; kw2++) {
#pragma unroll
            for (int kblk = 0; kblk < 4; kblk++) {
                int step = (kh * 3 + kw2) * 4 + kblk;
                short8 b0 = wp8[step * 256 + (ch * 2 + 0) * 64 + l];
                short8 b1 = wp8[step * 256 + (ch * 2 + 1) * 64 + l];
                int rbase = (row + kh) * LPLANB + kblk * 64 + lg * 16 + (kw2 + li) * LROWB;
#pragma unroll
                for (int pt = 0; pt < 4; pt++) {
                    short8 a = *reinterpret_cast<const short8*>(Abase + rbase + pt * (16 * LROWB));
                    acc[pt][0] = __builtin_amdgcn_mfma_f32_16x16x32_bf16(a, b0, acc[pt][0], 0, 0, 0);
                    acc[pt][1] = __builtin_amdgcn_mfma_f32_16x16x32_bf16(a, b1, acc[pt][1], 0, 0, 0);
                }
            }
        }
    }

    // ---- epilogue: C row = px = pt*16 + lg*4 + reg, col = co = ct*16 + li ----
    int h = h0 + row;
#pragma unroll
    for (int j = 0; j < 2; j++) {
        int co = (ch * 2 + j) * 16 + li;
        float* ob = fused + ((size_t)(bb * C_ + co) * H_ + h) * W_ + w0 + lg * 4;
#pragma unroll
        for (int pt = 0; pt < 4; pt++) {
            *reinterpret_cast<f32x4*>(ob + pt * 16) = acc[pt][j];
        }
    }
}

// ---------- 12. SE MLP ----------
__global__ __launch_bounds__(256) void k_se(const float* __restrict__ ymean,
    const float* __restrict__ w1, const float* __restrict__ w2, float* __restrict__ scale)
{
    __shared__ float h4[B_ * 4];
    int t = threadIdx.x;
    if (t < B_ * 4) {
        int b = t >> 2, o = t & 3;
        float a = 0.f;
        for (int c = 0; c < C_; c++) a += w1[o * C_ + c] * ymean[b * C_ + c];
        h4[b * 4 + o] = fmaxf(a, 0.f);
    }
    __syncthreads();
    {
        int b = t >> 6, c = t & 63;
        float a = 0.f;
        for (int o = 0; o < 4; o++) a += w2[c * 4 + o] * h4[b * 4 + o];
        scale[t] = sigm(a);
    }
}

// ---------- 13. final: x = elu(fused * scale) ----------
__global__ __launch_bounds__(256) void k_final(const float* __restrict__ fused,
    const float* __restrict__ scale, float* __restrict__ out)
{
    int idx = blockIdx.x * 256 + threadIdx.x;      // B_*C_*HW
    int bc = idx / HW;
    out[idx] = elu1(fused[idx] * scale[bc]);
}

extern "C" void kernel_launch(void* const* d_in, const int* in_sizes, int n_in,
                              void* d_out, int out_size, void* d_ws, size_t ws_size,
                              hipStream_t stream)
{
    const float* left   = (const float*)d_in[0];
    const float* right  = (const float*)d_in[1];
    const float* directs= (const float*)d_in[2];
    const float* qw     = (const float*)d_in[3];
    const float* q_g    = (const float*)d_in[4];
    const float* q_b    = (const float*)d_in[5];
    const float* kw     = (const float*)d_in[6];
    const float* k_g    = (const float*)d_in[7];
    const float* k_b    = (const float*)d_in[8];
    const float* gaw1   = (const float*)d_in[9];
    const float* gab1   = (const float*)d_in[10];
    const float* gaw2   = (const float*)d_in[11];
    const float* gab2   = (const float*)d_in[12];
    const float* law    = (const float*)d_in[13];
    const float* lab    = (const float*)d_in[14];
    const float* lag    = (const float*)d_in[15];
    const float* labb   = (const float*)d_in[16];
    const float* afw1   = (const float*)d_in[17];
    const float* afb1   = (const float*)d_in[18];
    const float* afw2   = (const float*)d_in[19];
    const float* afb2   = (const float*)d_in[20];
    const float* rdww   = (const float*)d_in[21];
    const float* rdwb   = (const float*)d_in[22];
    const float* rpww   = (const float*)d_in[23];
    const float* rpwb   = (const float*)d_in[24];
    const float* fuw    = (const float*)d_in[25];
    const float* fub    = (const float*)d_in[26];
    const float* sew1   = (const float*)d_in[27];
    const float* sew2   = (const float*)d_in[28];

    // workspace layout (floats). Peak use: 15,852,544 floats = 63.4 MB (same as proven round-1 footprint).
    float* ws    = (float*)d_ws;
    float* qraw  = ws + 0;          // B*RC*HW = 1,966,080 ; becomes q in-place
    float* kraw  = ws + 1966080;    // 1,966,080 ; reused as lraw after km
    float* km    = ws + 3932160;    // B*HW = 122,880
    float* vol   = ws + 4055040;    // B*D*HW = 5,898,240
    float* dwb   = ws + 9953280;    // B*D*HW = 5,898,240 (ends 15,851,520)
    float* smal  = ws + 15851520;   // 1024 floats of stats/small tensors
    float* fused = ws + 0;          // B*C*HW = 7,864,320 ; overlaps dead qraw/kraw/km/vol (safe: written after their last reads; ends 7,864,320 < dwb start)
    float* lraw  = kraw;
    // wpack: 73,728 bf16 = 36,864 float-slots carved from the TAIL of dwb.
    // dwb is dead after k_rpw; k_wpack runs after k_rpw and before k_fused_mfma.
    unsigned short* wpack = (unsigned short*)(ws + 15811584);   // ends 15,848,448 < 15,851,520

    float* stQ   = smal + 0;    // 64: (b,g) mean/invstd
    float* stK   = smal + 64;
    float* stL   = smal + 128;
    float* gp    = smal + 192;  // 64
    float* gbias = smal + 256;  // 64
    float* ymean = smal + 320;  // 256
    float* scal  = smal + 576;  // 256

    float* xout  = (float*)d_out;            // 7,864,320
    float* ncost = xout + 7864320;           // 5,898,240

    k_conv_qk<<<480, 256, 0, stream>>>(left, right, qw, kw, qraw, kraw);
    k_gn_stats<<<32, 256, 0, stream>>>(qraw, stQ);
    k_gn_stats<<<32, 256, 0, stream>>>(kraw, stK);
    k_gn_apply<<<7680, 256, 0, stream>>>(qraw, stQ, q_g, q_b);
    k_km<<<480, 256, 0, stream>>>(kraw, stK, k_g, k_b, km);
    k_rowmean<<<64, 256, 0, stream>>>(qraw, gp);
    k_gfeat<<<1, 64, 0, stream>>>(gp, gaw1, gab1, gaw2, gab2, afw1, afb1, gbias);
    k_conv_la<<<480, 256, 0, stream>>>(qraw, law, lab, lraw);
    k_gn_stats<<<32, 256, 0, stream>>>(lraw, stL);
    k_vol<<<480, 256, 0, stream>>>(lraw, stL, lag, labb, gbias, afw1, afw2, afb2, km, directs, vol);
    k_dw<<<23040, 256, 0, stream>>>(vol, rdww, rdwb, dwb);
    k_rpw<<<480, 256, 0, stream>>>(dwb, rpww, rpwb, ncost);
    k_wpack<<<36, 256, 0, stream>>>(fuw, wpack);
    k_fused_mfma<<<dim3(5, 48, 4), 256, 0, stream>>>(left, ncost, wpack, fub, fused);
    k_rowmean<<<256, 256, 0, stream>>>(fused, ymean);
    k_se<<<1, 256, 0, stream>>>(ymean, sew1, sew2, scal);
    k_final<<<30720, 256, 0, stream>>>(fused, scal, xout);
}

// Round 3
// 304.057 us; speedup vs baseline: 2.5196x; 1.7323x over previous
//
#include <hip/hip_runtime.h>
#include <math.h>

// ---- problem constants ----
static constexpr int B_  = 4;
static constexpr int C_  = 64;
static constexpr int H_  = 96;
static constexpr int W_  = 320;
static constexpr int HW  = H_ * W_;          // 30720
static constexpr int RCH = 16;               // RC = C/4
static constexpr int D_  = 48;
static constexpr int NG  = 8;                // groupnorm groups
static constexpr int CPG = RCH / NG;         // 2 channels per group
static constexpr float EPS_ = 1e-5f;
static constexpr int APX = 322;              // abf padded px count (w = -1..320)

typedef __attribute__((ext_vector_type(8))) short short8;
typedef __attribute__((ext_vector_type(4))) float f32x4;
typedef __attribute__((ext_vector_type(4))) unsigned int u32x4;

__device__ __forceinline__ float elu1(float x) { return x > 0.f ? x : __expf(x) - 1.f; }
__device__ __forceinline__ float sigm(float x) { return 1.f / (1.f + __expf(-x)); }
__device__ __forceinline__ unsigned bf16rne(float f) {
    unsigned u = __builtin_bit_cast(unsigned, f);
    u += 0x7fffu + ((u >> 16) & 1u);
    return u >> 16;
}
__device__ __forceinline__ void gload16(const void* g, void* l) {
    __builtin_amdgcn_global_load_lds((const __attribute__((address_space(1))) unsigned int*)g,
                                     (__attribute__((address_space(3))) unsigned int*)l, 16, 0, 0);
}

// ---------- 1. 1x1 conv: left->qraw, right->kraw (no bias) ----------
__global__ __launch_bounds__(256) void k_conv_qk(
    const float* __restrict__ left, const float* __restrict__ right,
    const float* __restrict__ qw, const float* __restrict__ kw,
    float* __restrict__ qraw, float* __restrict__ kraw)
{
    __shared__ float swq[RCH * C_], swk[RCH * C_];
    for (int i = threadIdx.x; i < RCH * C_; i += 256) { swq[i] = qw[i]; swk[i] = kw[i]; }
    __syncthreads();
    int idx = blockIdx.x * 256 + threadIdx.x;      // exactly B_*HW threads
    int b = idx / HW, p = idx - b * HW;
    const float* lb = left  + (size_t)b * C_ * HW + p;
    const float* rb = right + (size_t)b * C_ * HW + p;
    float aq[RCH], ak[RCH];
#pragma unroll
    for (int r = 0; r < RCH; r++) { aq[r] = 0.f; ak[r] = 0.f; }
    for (int c = 0; c < C_; c++) {
        float lv = lb[(size_t)c * HW];
        float rv = rb[(size_t)c * HW];
#pragma unroll
        for (int r = 0; r < RCH; r++) {
            aq[r] += lv * swq[r * C_ + c];
            ak[r] += rv * swk[r * C_ + c];
        }
    }
#pragma unroll
    for (int r = 0; r < RCH; r++) {
        qraw[((size_t)b * RCH + r) * HW + p] = aq[r];
        kraw[((size_t)b * RCH + r) * HW + p] = ak[r];
    }
}

// ---------- 2. group-norm stats: one block per (b,g), float4 ----------
__global__ __launch_bounds__(256) void k_gn_stats(const float* __restrict__ src, float* __restrict__ stats)
{
    int b = blockIdx.x / NG, g = blockIdx.x % NG;
    const float4* base = (const float4*)(src + ((size_t)b * RCH + g * CPG) * HW);
    float s = 0.f, ss = 0.f;
    for (int i = threadIdx.x; i < CPG * HW / 4; i += 256) {
        float4 v = base[i];
        s  += v.x + v.y + v.z + v.w;
        ss += v.x * v.x + v.y * v.y + v.z * v.z + v.w * v.w;
    }
    __shared__ float rs[256], rq[256];
    rs[threadIdx.x] = s; rq[threadIdx.x] = ss; __syncthreads();
    for (int off = 128; off > 0; off >>= 1) {
        if (threadIdx.x < off) { rs[threadIdx.x] += rs[threadIdx.x + off]; rq[threadIdx.x] += rq[threadIdx.x + off]; }
        __syncthreads();
    }
    if (threadIdx.x == 0) {
        float inv = 1.f / (float)(CPG * HW);
        float m = rs[0] * inv;
        float var = rq[0] * inv - m * m;
        stats[blockIdx.x * 2 + 0] = m;
        stats[blockIdx.x * 2 + 1] = rsqrtf(var + EPS_);
    }
}

// ---------- 3. GN apply + elu, in place (for q), float4 ----------
__global__ __launch_bounds__(256) void k_gn_apply(float* __restrict__ x, const float* __restrict__ stats,
    const float* __restrict__ gam, const float* __restrict__ bet)
{
    int idx4 = blockIdx.x * 256 + threadIdx.x;     // B_*RCH*HW/4 threads
    int b = idx4 / (RCH * HW / 4);
    int rc = (idx4 / (HW / 4)) % RCH;
    int g = rc >> 1;
    float m = stats[(b * NG + g) * 2], is = stats[(b * NG + g) * 2 + 1];
    float ga = gam[rc] * is, be = bet[rc] - m * is * gam[rc];
    float4 v = ((const float4*)x)[idx4];
    v.x = elu1(v.x * ga + be); v.y = elu1(v.y * ga + be);
    v.z = elu1(v.z * ga + be); v.w = elu1(v.w * ga + be);
    ((float4*)x)[idx4] = v;
}

// ---------- 4. km = mean over channels of elu(GN(kraw)) ----------
__global__ __launch_bounds__(256) void k_km(const float* __restrict__ kraw, const float* __restrict__ stats,
    const float* __restrict__ gam, const float* __restrict__ bet, float* __restrict__ km)
{
    int idx = blockIdx.x * 256 + threadIdx.x;      // B_*HW
    int b = idx / HW, p = idx - b * HW;
    float s = 0.f;
#pragma unroll
    for (int rc = 0; rc < RCH; rc++) {
        int g = rc >> 1;
        float m = stats[(b * NG + g) * 2], is = stats[(b * NG + g) * 2 + 1];
        float v = (kraw[((size_t)b * RCH + rc) * HW + p] - m) * is * gam[rc] + bet[rc];
        s += elu1(v);
    }
    km[idx] = s * (1.f / (float)RCH);
}

// ---------- 5. per-row mean over HW (used for gp and ymean), float4 ----------
__global__ __launch_bounds__(256) void k_rowmean(const float* __restrict__ src, float* __restrict__ out)
{
    const float4* base = (const float4*)(src + (size_t)blockIdx.x * HW);
    float s = 0.f;
    for (int p = threadIdx.x; p < HW / 4; p += 256) {
        float4 v = base[p];
        s += v.x + v.y + v.z + v.w;
    }
    __shared__ float red[256];
    red[threadIdx.x] = s; __syncthreads();
    for (int off = 128; off > 0; off >>= 1) {
        if (threadIdx.x < off) red[threadIdx.x] += red[threadIdx.x + off];
        __syncthreads();
    }
    if (threadIdx.x == 0) out[blockIdx.x] = red[0] * (1.f / (float)HW);
}

// ---------- 6. gfeat MLP + fold into attn-hidden bias: gbias[b,o] ----------
__global__ __launch_bounds__(64) void k_gfeat(const float* __restrict__ gp,
    const float* __restrict__ gaw1, const float* __restrict__ gab1,
    const float* __restrict__ gaw2, const float* __restrict__ gab2,
    const float* __restrict__ afw1, const float* __restrict__ afb1,
    float* __restrict__ gbias)
{
    __shared__ float g1[B_ * 8], gf[B_ * RCH];
    int t = threadIdx.x;
    if (t < B_ * 8) {
        int b = t >> 3, o = t & 7;
        float a = gab1[o];
        for (int i = 0; i < RCH; i++) a += gaw1[o * RCH + i] * gp[b * RCH + i];
        g1[b * 8 + o] = elu1(a);
    }
    __syncthreads();
    {
        int b = t >> 4, o = t & 15;
        float a = gab2[o];
        for (int i = 0; i < 8; i++) a += gaw2[o * 8 + i] * g1[b * 8 + i];
        gf[t] = a;
    }
    __syncthreads();
    {
        int b = t >> 4, o = t & 15;
        float a = afb1[o];
        for (int i = 0; i < RCH; i++) a += afw1[o * 2 * RCH + i] * gf[b * RCH + i];
        gbias[t] = a;
    }
}

// ---------- 7. 3x3 conv q -> lraw (zero pad, bias) ----------
__global__ __launch_bounds__(256) void k_conv_la(const float* __restrict__ q,
    const float* __restrict__ law, const float* __restrict__ lab, float* __restrict__ lraw)
{
    __shared__ float wl[RCH * RCH * 9];   // 2304
    for (int i = threadIdx.x; i < RCH * RCH * 9; i += 256) wl[i] = law[i];
    __syncthreads();
    int idx = blockIdx.x * 256 + threadIdx.x;      // B_*HW
    int b = idx / HW, p = idx - b * HW;
    int h = p / W_, w = p - h * W_;
    float acc[RCH];
#pragma unroll
    for (int co = 0; co < RCH; co++) acc[co] = lab[co];
    for (int ci = 0; ci < RCH; ci++) {
        const float* qb = q + ((size_t)b * RCH + ci) * HW;
#pragma unroll
        for (int kh = 0; kh < 3; kh++) {
            int hh = h + kh - 1;
            if (hh < 0 || hh >= H_) continue;
            float a0 = (w - 1 >= 0) ? qb[hh * W_ + w - 1] : 0.f;
            float a1 = qb[hh * W_ + w];
            float a2 = (w + 1 < W_) ? qb[hh * W_ + w + 1] : 0.f;
#pragma unroll
            for (int co = 0; co < RCH; co++) {
                const float* wp = &wl[(co * RCH + ci) * 9 + kh * 3];
                acc[co] += a0 * wp[0] + a1 * wp[1] + a2 * wp[2];
            }
        }
    }
#pragma unroll
    for (int co = 0; co < RCH; co++) lraw[((size_t)b * RCH + co) * HW + p] = acc[co];
}

// ---------- 8. fused: GN(lraw)+elu -> attn MLP -> sigmoid; warp km; vol ----------
__global__ __launch_bounds__(256) void k_vol(const float* __restrict__ lraw,
    const float* __restrict__ stats, const float* __restrict__ lg, const float* __restrict__ lb,
    const float* __restrict__ gbias, const float* __restrict__ afw1,
    const float* __restrict__ afw2, const float* __restrict__ afb2,
    const float* __restrict__ km, const float* __restrict__ directs, float* __restrict__ vol)
{
    __shared__ float w1[RCH * 2 * RCH];   // 512
    __shared__ float w2[D_ * RCH];        // 768
    __shared__ float b2[D_];
    for (int i = threadIdx.x; i < RCH * 2 * RCH; i += 256) w1[i] = afw1[i];
    for (int i = threadIdx.x; i < D_ * RCH; i += 256) w2[i] = afw2[i];
    if (threadIdx.x < D_) b2[threadIdx.x] = afb2[threadIdx.x];
    __syncthreads();
    int idx = blockIdx.x * 256 + threadIdx.x;      // B_*HW
    int b = idx / HW, p = idx - b * HW;
    int h = p / W_, w = p - h * W_;
    float lf[RCH];
#pragma unroll
    for (int rc = 0; rc < RCH; rc++) {
        int g = rc >> 1;
        float m = stats[(b * NG + g) * 2], is = stats[(b * NG + g) * 2 + 1];
        lf[rc] = elu1((lraw[((size_t)b * RCH + rc) * HW + p] - m) * is * lg[rc] + lb[rc]);
    }
    float hid[RCH];
#pragma unroll
    for (int o = 0; o < RCH; o++) {
        float a = gbias[b * RCH + o];
#pragma unroll
        for (int i = 0; i < RCH; i++) a += w1[o * 2 * RCH + RCH + i] * lf[i];
        hid[o] = elu1(a);
    }
    const float* kmrow = km + (size_t)b * HW + h * W_;
    float dir = directs[b];
    for (int d = 0; d < D_; d++) {
        float a = b2[d];
#pragma unroll
        for (int o = 0; o < RCH; o++) a += w2[d * RCH + o] * hid[o];
        float s = sigm(a);
        float shift = ((float)d / 160.f) * dir * (float)(W_ - 1);
        float pos = (float)w + shift;
        float x0 = floorf(pos);
        float f = pos - x0;
        float c0 = fminf(fmaxf(x0, 0.f), (float)(W_ - 1));
        float c1 = fminf(fmaxf(x0 + 1.f, 0.f), (float)(W_ - 1));
        int i0 = (int)c0, i1 = (int)c1;
        float wv = kmrow[i0] * (1.f - f) + kmrow[i1] * f;
        vol[((size_t)(b * D_ + d)) * HW + p] = wv * s;
    }
}

// ---------- 9. depthwise 3x3 + elu, 4 px/thread ----------
__global__ __launch_bounds__(256) void k_dw(const float* __restrict__ vol,
    const float* __restrict__ wgt, const float* __restrict__ bias, float* __restrict__ dwout)
{
    int idx = blockIdx.x * 256 + threadIdx.x;      // B_*D_*HW/4
    int p4 = idx % (HW / 4);
    int d  = (idx / (HW / 4)) % D_;
    int b  = idx / (D_ * HW / 4);
    int h = p4 / (W_ / 4), w = (p4 % (W_ / 4)) * 4;
    const float* vb = vol + ((size_t)(b * D_ + d)) * HW;
    float wz[9];
#pragma unroll
    for (int i = 0; i < 9; i++) wz[i] = wgt[d * 9 + i];
    float bv = bias[d];
    float acc[4] = {bv, bv, bv, bv};
#pragma unroll
    for (int r = 0; r < 3; r++) {
        int hh = h + r - 1;
        if (hh < 0 || hh >= H_) continue;
        const float* row = vb + hh * W_;
        float4 c = *(const float4*)(row + w);
        float in6[6];
        in6[0] = (w > 0) ? row[w - 1] : 0.f;
        in6[1] = c.x; in6[2] = c.y; in6[3] = c.z; in6[4] = c.w;
        in6[5] = (w + 4 < W_) ? row[w + 4] : 0.f;
#pragma unroll
        for (int j = 0; j < 4; j++)
            acc[j] += in6[j] * wz[r * 3] + in6[j + 1] * wz[r * 3 + 1] + in6[j + 2] * wz[r * 3 + 2];
    }
    float4 o;
    o.x = elu1(acc[0]); o.y = elu1(acc[1]); o.z = elu1(acc[2]); o.w = elu1(acc[3]);
    ((float4*)dwout)[idx] = o;
}

// ---------- 9b. prep: abf[b][h][322][120ci] bf16 — left channels (dw 0..31) + zero pad (dw 56..59) ----------
__global__ __launch_bounds__(256) void k_prep(const float* __restrict__ left, unsigned int* __restrict__ abf)
{
    int idx = blockIdx.x * 256 + threadIdx.x;      // B_*H_*APX = 123,648 exactly
    int px = idx % APX;
    int bh = idx / APX;
    int b = bh / H_, h = bh % H_;
    int w = px - 1;
    w = w < 0 ? -w : (w >= W_ ? 2 * W_ - 2 - w : w);
    const float* src = left + (size_t)b * C_ * HW + h * W_ + w;
    unsigned int* dst = abf + (size_t)idx * 60;
#pragma unroll
    for (int q4 = 0; q4 < 8; q4++) {
        u32x4 t;
#pragma unroll
        for (int z = 0; z < 4; z++) {
            int ci = (q4 * 4 + z) * 2;
            float f0 = src[(size_t)ci * HW];
            float f1 = src[(size_t)(ci + 1) * HW];
            t[z] = bf16rne(f0) | (bf16rne(f1) << 16);
        }
        *reinterpret_cast<u32x4*>(dst + q4 * 4) = t;
    }
    *reinterpret_cast<u32x4*>(dst + 56) = (u32x4){0u, 0u, 0u, 0u};
}

// ---------- 10. 1x1 48->48 + softmax -> norm_cost ; also writes abf dwords 32..55 ----------
__global__ __launch_bounds__(256) void k_rpw(const float* __restrict__ dwin,
    const float* __restrict__ wgt, const float* __restrict__ bias,
    float* __restrict__ ncost, unsigned int* __restrict__ abf)
{
    __shared__ float wr[D_ * D_];   // 2304
    for (int i = threadIdx.x; i < D_ * D_; i += 256) wr[i] = wgt[i];
    __syncthreads();
    int idx = blockIdx.x * 256 + threadIdx.x;      // B_*HW
    int b = idx / HW, p = idx - b * HW;
    int h = p / W_, w = p - h * W_;
    float v[D_];
#pragma unroll
    for (int i = 0; i < D_; i++) v[i] = dwin[((size_t)(b * D_ + i)) * HW + p];
    float cst[D_];
    float mx = -1e30f;
    for (int d = 0; d < D_; d++) {
        float a = bias[d];
#pragma unroll
        for (int i = 0; i < D_; i++) a += wr[d * D_ + i] * v[i];
        cst[d] = a; mx = fmaxf(mx, a);
    }
    float s = 0.f;
#pragma unroll
    for (int d = 0; d < D_; d++) { float e = __expf(cst[d] - mx); cst[d] = e; s += e; }
    float inv = 1.f / s;
#pragma unroll
    for (int d = 0; d < D_; d++) {
        cst[d] *= inv;
        ncost[((size_t)(b * D_ + d)) * HW + p] = cst[d];
    }
    // pack into abf (ci 64..111 -> dwords 32..55)
    u32x4 pk[6];
#pragma unroll
    for (int q4 = 0; q4 < 6; q4++)
#pragma unroll
        for (int z = 0; z < 4; z++) {
            int d = (q4 * 4 + z) * 2;
            pk[q4][z] = bf16rne(cst[d]) | (bf16rne(cst[d + 1]) << 16);
        }
    size_t bh322 = (size_t)(b * H_ + h) * APX;
    unsigned int* dst = abf + (bh322 + (w + 1)) * 60 + 32;
#pragma unroll
    for (int q4 = 0; q4 < 6; q4++) *reinterpret_cast<u32x4*>(dst + q4 * 4) = pk[q4];
    if (w == 1 || w == W_ - 2) {
        unsigned int* dst2 = abf + (bh322 + (w == 1 ? 0 : APX - 1)) * 60 + 32;
#pragma unroll
        for (int q4 = 0; q4 < 6; q4++) *reinterpret_cast<u32x4*>(dst2 + q4 * 4) = pk[q4];
    }
}

// ---------- 11a. weight prepack for MFMA fused conv ----------
// wpack[step(36)][ct(4)][lane(64)][j(8)] bf16, step = (kh*3+kw)*4 + kblk
// B[k][n]: k = kblk*32 + (lane>>4)*8 + j (ci, 128-padded), n = ct*16 + (lane&15) (co)
__global__ __launch_bounds__(256) void k_wpack(const float* __restrict__ fw, unsigned short* __restrict__ wpack)
{
    int bi = blockIdx.x;           // 0..35
    int tap = bi >> 2, kblk = bi & 3;
    int kh = tap / 3, kw2 = tap % 3;
    int t = threadIdx.x;
    int ct = t >> 6, l = t & 63;
    int co = ct * 16 + (l & 15);
    int ci0 = kblk * 32 + ((l >> 4) & 3) * 8;
    unsigned short v[8];
#pragma unroll
    for (int j = 0; j < 8; j++) {
        int ci = ci0 + j;
        float f = (ci < 112) ? fw[((size_t)(co * 112 + ci)) * 9 + kh * 3 + kw2] : 0.f;
        v[j] = (unsigned short)bf16rne(f);
    }
    *reinterpret_cast<short8*>(wpack + ((size_t)bi * 256 + t) * 8) = *reinterpret_cast<short8*>(v);
}

// ---------- 11b. fused 3x3 conv 112->64, reflect pad, bf16 MFMA implicit GEMM ----------
// Block: 2 output rows x 64 px x 64 co. 4 waves: wave = (row, co-half).
// A staged from abf via global_load_lds: 4 planes x 66 px x 240 B, fully contiguous.
static constexpr int LROWB  = 240;           // bytes per px (120 bf16)
static constexpr int LPLANB = 66 * LROWB;    // 15840 bytes per input row
__global__ __launch_bounds__(256, 1) void k_fused_mfma(
    const unsigned int* __restrict__ abf,
    const unsigned short* __restrict__ wpack, const float* __restrict__ fb,
    float* __restrict__ fused)
{
    __shared__ __align__(16) unsigned int Atile4[15844];   // 63376 B (incl 16B overread pad)
    int bb = blockIdx.z;
    int h0 = blockIdx.y * 2;
    int w0 = blockIdx.x * 64;
    int tid = threadIdx.x;
    int wid = tid >> 6;          // wave id
    int l   = tid & 63;

    // ---- stage plane `wid` (input row h0-1+wid, reflect) ----
    {
        int hh = h0 - 1 + wid;
        hh = hh < 0 ? -hh : (hh >= H_ ? 2 * H_ - 2 - hh : hh);
        const char* gsrc = (const char*)(abf + ((size_t)(bb * H_ + hh) * APX + w0) * 60);
        char* lbase = (char*)Atile4 + wid * LPLANB;
#pragma unroll
        for (int i = 0; i < 15; i++)
            gload16(gsrc + (i * 64 + l) * 16, lbase + i * 1024);
        if (l < 30) gload16(gsrc + (960 + l) * 16, lbase + 15 * 1024);
    }
    __syncthreads();

    int row = wid >> 1;          // output row within block (0..1)
    int ch  = wid & 1;           // co half (0..1)
    int li = l & 15, lg = l >> 4;

    const short8* __restrict__ wp8 = reinterpret_cast<const short8*>(wpack);

    f32x4 acc[4][2];
    float bv0 = fb[(ch * 2 + 0) * 16 + li];
    float bv1 = fb[(ch * 2 + 1) * 16 + li];
#pragma unroll
    for (int pt = 0; pt < 4; pt++) {
        acc[pt][0] = (f32x4){bv0, bv0, bv0, bv0};
        acc[pt][1] = (f32x4){bv1, bv1, bv1, bv1};
    }

    const char* Abase = (const char*)Atile4;
#pragma unroll
    for (int kh = 0; kh < 3; kh++) {
#pragma unroll
        for (int kw2 = 0; kw2 < 3; kw2++) {
#pragma unroll
            for (int kblk = 0; kblk < 4; kblk++) {
                int step = (kh * 3 + kw2) * 4 + kblk;
                short8 b0 = wp8[step * 256 + (ch * 2 + 0) * 64 + l];
                short8 b1 = wp8[step * 256 + (ch * 2 + 1) * 64 + l];
                int rbase = (row + kh) * LPLANB + kblk * 64 + lg * 16 + (kw2 + li) * LROWB;
#pragma unroll
                for (int pt = 0; pt < 4; pt++) {
                    short8 a = *reinterpret_cast<const short8*>(Abase + rbase + pt * (16 * LROWB));
                    acc[pt][0] = __builtin_amdgcn_mfma_f32_16x16x32_bf16(a, b0, acc[pt][0], 0, 0, 0);
                    acc[pt][1] = __builtin_amdgcn_mfma_f32_16x16x32_bf16(a, b1, acc[pt][1], 0, 0, 0);
                }
            }
        }
    }

    // ---- epilogue: C row = px = pt*16 + lg*4 + reg, col = co = ct*16 + li ----
    int h = h0 + row;
#pragma unroll
    for (int j = 0; j < 2; j++) {
        int co = (ch * 2 + j) * 16 + li;
        float* ob = fused + ((size_t)(bb * C_ + co) * H_ + h) * W_ + w0 + lg * 4;
#pragma unroll
        for (int pt = 0; pt < 4; pt++) {
            *reinterpret_cast<f32x4*>(ob + pt * 16) = acc[pt][j];
        }
    }
}

// ---------- 12. SE MLP ----------
__global__ __launch_bounds__(256) void k_se(const float* __restrict__ ymean,
    const float* __restrict__ w1, const float* __restrict__ w2, float* __restrict__ scale)
{
    __shared__ float h4[B_ * 4];
    int t = threadIdx.x;
    if (t < B_ * 4) {
        int b = t >> 2, o = t & 3;
        float a = 0.f;
        for (int c = 0; c < C_; c++) a += w1[o * C_ + c] * ymean[b * C_ + c];
        h4[b * 4 + o] = fmaxf(a, 0.f);
    }
    __syncthreads();
    {
        int b = t >> 6, c = t & 63;
        float a = 0.f;
        for (int o = 0; o < 4; o++) a += w2[c * 4 + o] * h4[b * 4 + o];
        scale[t] = sigm(a);
    }
}

// ---------- 13. final: x = elu(fused * scale), float4 ----------
__global__ __launch_bounds__(256) void k_final(const float* __restrict__ fused,
    const float* __restrict__ scale, float* __restrict__ out)
{
    int idx4 = blockIdx.x * 256 + threadIdx.x;     // B_*C_*HW/4
    int bc = idx4 / (HW / 4);
    float sc = scale[bc];
    float4 v = ((const float4*)fused)[idx4];
    v.x = elu1(v.x * sc); v.y = elu1(v.y * sc);
    v.z = elu1(v.z * sc); v.w = elu1(v.w * sc);
    ((float4*)out)[idx4] = v;
}

extern "C" void kernel_launch(void* const* d_in, const int* in_sizes, int n_in,
                              void* d_out, int out_size, void* d_ws, size_t ws_size,
                              hipStream_t stream)
{
    const float* left   = (const float*)d_in[0];
    const float* right  = (const float*)d_in[1];
    const float* directs= (const float*)d_in[2];
    const float* qw     = (const float*)d_in[3];
    const float* q_g    = (const float*)d_in[4];
    const float* q_b    = (const float*)d_in[5];
    const float* kw     = (const float*)d_in[6];
    const float* k_g    = (const float*)d_in[7];
    const float* k_b    = (const float*)d_in[8];
    const float* gaw1   = (const float*)d_in[9];
    const float* gab1   = (const float*)d_in[10];
    const float* gaw2   = (const float*)d_in[11];
    const float* gab2   = (const float*)d_in[12];
    const float* law    = (const float*)d_in[13];
    const float* lab    = (const float*)d_in[14];
    const float* lag    = (const float*)d_in[15];
    const float* labb   = (const float*)d_in[16];
    const float* afw1   = (const float*)d_in[17];
    const float* afb1   = (const float*)d_in[18];
    const float* afw2   = (const float*)d_in[19];
    const float* afb2   = (const float*)d_in[20];
    const float* rdww   = (const float*)d_in[21];
    const float* rdwb   = (const float*)d_in[22];
    const float* rpww   = (const float*)d_in[23];
    const float* rpwb   = (const float*)d_in[24];
    const float* fuw    = (const float*)d_in[25];
    const float* fub    = (const float*)d_in[26];
    const float* sew1   = (const float*)d_in[27];
    const float* sew2   = (const float*)d_in[28];

    // workspace layout (floats). Peak 15,852,544 floats = 63.4 MB (same proven footprint).
    // Phase A (through k_dw):  qraw[0..1.97M) kraw[1.97..3.93M) km[3.93..4.06M) vol[4.06..9.95M) dwb[9.95..15.85M)
    // Phase B (k_prep onward): abf[0..7.42M) (over dead qraw/kraw/km/vol-start), dwb still live until k_rpw
    // Phase C (k_fused_mfma):  fused[7.42M..15.28M) (over dead vol-tail/dwb), abf still live, wpack at 15.81M
    float* ws    = (float*)d_ws;
    float* qraw  = ws + 0;
    float* kraw  = ws + 1966080;
    float* km    = ws + 3932160;
    float* vol   = ws + 4055040;
    float* dwb   = ws + 9953280;          // ends 15,851,520
    float* smal  = ws + 15851520;         // 1024 floats
    unsigned int* abf = (unsigned int*)(ws + 0);       // B*H*322*60 dwords = 7,418,880 floats
    float* fused = ws + 7418880;          // 7,864,320 -> ends 15,283,200
    float* lraw  = kraw;
    unsigned short* wpack = (unsigned short*)(ws + 15811584);  // 73,728 bf16, ends 15,848,448

    float* stQ   = smal + 0;
    float* stK   = smal + 64;
    float* stL   = smal + 128;
    float* gp    = smal + 192;
    float* gbias = smal + 256;
    float* ymean = smal + 320;
    float* scal  = smal + 576;

    float* xout  = (float*)d_out;            // 7,864,320
    float* ncost = xout + 7864320;           // 5,898,240

    k_conv_qk<<<480, 256, 0, stream>>>(left, right, qw, kw, qraw, kraw);
    k_gn_stats<<<32, 256, 0, stream>>>(qraw, stQ);
    k_gn_stats<<<32, 256, 0, stream>>>(kraw, stK);
    k_gn_apply<<<1920, 256, 0, stream>>>(qraw, stQ, q_g, q_b);
    k_km<<<480, 256, 0, stream>>>(kraw, stK, k_g, k_b, km);
    k_rowmean<<<64, 256, 0, stream>>>(qraw, gp);
    k_gfeat<<<1, 64, 0, stream>>>(gp, gaw1, gab1, gaw2, gab2, afw1, afb1, gbias);
    k_conv_la<<<480, 256, 0, stream>>>(qraw, law, lab, lraw);
    k_gn_stats<<<32, 256, 0, stream>>>(lraw, stL);
    k_vol<<<480, 256, 0, stream>>>(lraw, stL, lag, labb, gbias, afw1, afw2, afb2, km, directs, vol);
    k_dw<<<5760, 256, 0, stream>>>(vol, rdww, rdwb, dwb);
    k_prep<<<483, 256, 0, stream>>>(left, abf);
    k_rpw<<<480, 256, 0, stream>>>(dwb, rpww, rpwb, ncost, abf);
    k_wpack<<<36, 256, 0, stream>>>(fuw, wpack);
    k_fused_mfma<<<dim3(5, 48, 4), 256, 0, stream>>>(abf, wpack, fub, fused);
    k_rowmean<<<256, 256, 0, stream>>>(fused, ymean);
    k_se<<<1, 256, 0, stream>>>(ymean, sew1, sew2, scal);
    k_final<<<7680, 256, 0, stream>>>(fused, scal, xout);
}

// Round 4
// 285.727 us; speedup vs baseline: 2.6812x; 1.0642x over previous
//
#include <hip/hip_runtime.h>
#include <math.h>

// ---- problem constants ----
static constexpr int B_  = 4;
static constexpr int C_  = 64;
static constexpr int H_  = 96;
static constexpr int W_  = 320;
static constexpr int HW  = H_ * W_;          // 30720
static constexpr int RCH = 16;               // RC = C/4
static constexpr int D_  = 48;
static constexpr int NG  = 8;                // groupnorm groups
static constexpr int CPG = RCH / NG;         // 2 channels per group
static constexpr float EPS_ = 1e-5f;
static constexpr int APX = 322;              // abf padded px count (w = -1..320)

typedef __attribute__((ext_vector_type(8))) short short8;
typedef __attribute__((ext_vector_type(4))) float f32x4;
typedef __attribute__((ext_vector_type(4))) unsigned int u32x4;

__device__ __forceinline__ float elu1(float x) { return x > 0.f ? x : __expf(x) - 1.f; }
__device__ __forceinline__ float sigm(float x) { return 1.f / (1.f + __expf(-x)); }
__device__ __forceinline__ unsigned bf16rne(float f) {
    unsigned u = __builtin_bit_cast(unsigned, f);
    u += 0x7fffu + ((u >> 16) & 1u);
    return u >> 16;
}
__device__ __forceinline__ void gload16(const void* g, void* l) {
    __builtin_amdgcn_global_load_lds((const __attribute__((address_space(1))) unsigned int*)g,
                                     (__attribute__((address_space(3))) unsigned int*)l, 16, 0, 0);
}

// ---------- 1. 1x1 conv: left->qraw, right->kraw (no bias) ----------
__global__ __launch_bounds__(256) void k_conv_qk(
    const float* __restrict__ left, const float* __restrict__ right,
    const float* __restrict__ qw, const float* __restrict__ kw,
    float* __restrict__ qraw, float* __restrict__ kraw)
{
    __shared__ float swq[RCH * C_], swk[RCH * C_];
    for (int i = threadIdx.x; i < RCH * C_; i += 256) { swq[i] = qw[i]; swk[i] = kw[i]; }
    __syncthreads();
    int idx = blockIdx.x * 256 + threadIdx.x;      // exactly B_*HW threads
    int b = idx / HW, p = idx - b * HW;
    const float* lb = left  + (size_t)b * C_ * HW + p;
    const float* rb = right + (size_t)b * C_ * HW + p;
    float aq[RCH], ak[RCH];
#pragma unroll
    for (int r = 0; r < RCH; r++) { aq[r] = 0.f; ak[r] = 0.f; }
    for (int c = 0; c < C_; c++) {
        float lv = lb[(size_t)c * HW];
        float rv = rb[(size_t)c * HW];
#pragma unroll
        for (int r = 0; r < RCH; r++) {
            aq[r] += lv * swq[r * C_ + c];
            ak[r] += rv * swk[r * C_ + c];
        }
    }
#pragma unroll
    for (int r = 0; r < RCH; r++) {
        qraw[((size_t)b * RCH + r) * HW + p] = aq[r];
        kraw[((size_t)b * RCH + r) * HW + p] = ak[r];
    }
}

// ---------- 2. group-norm stats: one block per (b,g), float4 ----------
__global__ __launch_bounds__(256) void k_gn_stats(const float* __restrict__ src, float* __restrict__ stats)
{
    int b = blockIdx.x / NG, g = blockIdx.x % NG;
    const float4* base = (const float4*)(src + ((size_t)b * RCH + g * CPG) * HW);
    float s = 0.f, ss = 0.f;
    for (int i = threadIdx.x; i < CPG * HW / 4; i += 256) {
        float4 v = base[i];
        s  += v.x + v.y + v.z + v.w;
        ss += v.x * v.x + v.y * v.y + v.z * v.z + v.w * v.w;
    }
    __shared__ float rs[256], rq[256];
    rs[threadIdx.x] = s; rq[threadIdx.x] = ss; __syncthreads();
    for (int off = 128; off > 0; off >>= 1) {
        if (threadIdx.x < off) { rs[threadIdx.x] += rs[threadIdx.x + off]; rq[threadIdx.x] += rq[threadIdx.x + off]; }
        __syncthreads();
    }
    if (threadIdx.x == 0) {
        float inv = 1.f / (float)(CPG * HW);
        float m = rs[0] * inv;
        float var = rq[0] * inv - m * m;
        stats[blockIdx.x * 2 + 0] = m;
        stats[blockIdx.x * 2 + 1] = rsqrtf(var + EPS_);
    }
}

// ---------- 3. GN apply + elu, in place (for q), float4 ----------
__global__ __launch_bounds__(256) void k_gn_apply(float* __restrict__ x, const float* __restrict__ stats,
    const float* __restrict__ gam, const float* __restrict__ bet)
{
    int idx4 = blockIdx.x * 256 + threadIdx.x;     // B_*RCH*HW/4 threads
    int b = idx4 / (RCH * HW / 4);
    int rc = (idx4 / (HW / 4)) % RCH;
    int g = rc >> 1;
    float m = stats[(b * NG + g) * 2], is = stats[(b * NG + g) * 2 + 1];
    float ga = gam[rc] * is, be = bet[rc] - m * is * gam[rc];
    float4 v = ((const float4*)x)[idx4];
    v.x = elu1(v.x * ga + be); v.y = elu1(v.y * ga + be);
    v.z = elu1(v.z * ga + be); v.w = elu1(v.w * ga + be);
    ((float4*)x)[idx4] = v;
}

// ---------- 4. km = mean over channels of elu(GN(kraw)) ----------
__global__ __launch_bounds__(256) void k_km(const float* __restrict__ kraw, const float* __restrict__ stats,
    const float* __restrict__ gam, const float* __restrict__ bet, float* __restrict__ km)
{
    int idx = blockIdx.x * 256 + threadIdx.x;      // B_*HW
    int b = idx / HW, p = idx - b * HW;
    float s = 0.f;
#pragma unroll
    for (int rc = 0; rc < RCH; rc++) {
        int g = rc >> 1;
        float m = stats[(b * NG + g) * 2], is = stats[(b * NG + g) * 2 + 1];
        float v = (kraw[((size_t)b * RCH + rc) * HW + p] - m) * is * gam[rc] + bet[rc];
        s += elu1(v);
    }
    km[idx] = s * (1.f / (float)RCH);
}

// ---------- 5. per-row mean over HW (used for gp and ymean), float4 ----------
__global__ __launch_bounds__(256) void k_rowmean(const float* __restrict__ src, float* __restrict__ out)
{
    const float4* base = (const float4*)(src + (size_t)blockIdx.x * HW);
    float s = 0.f;
    for (int p = threadIdx.x; p < HW / 4; p += 256) {
        float4 v = base[p];
        s += v.x + v.y + v.z + v.w;
    }
    __shared__ float red[256];
    red[threadIdx.x] = s; __syncthreads();
    for (int off = 128; off > 0; off >>= 1) {
        if (threadIdx.x < off) red[threadIdx.x] += red[threadIdx.x + off];
        __syncthreads();
    }
    if (threadIdx.x == 0) out[blockIdx.x] = red[0] * (1.f / (float)HW);
}

// ---------- 6. gfeat MLP + fold into attn-hidden bias: gbias[b,o] ----------
__global__ __launch_bounds__(64) void k_gfeat(const float* __restrict__ gp,
    const float* __restrict__ gaw1, const float* __restrict__ gab1,
    const float* __restrict__ gaw2, const float* __restrict__ gab2,
    const float* __restrict__ afw1, const float* __restrict__ afb1,
    float* __restrict__ gbias)
{
    __shared__ float g1[B_ * 8], gf[B_ * RCH];
    int t = threadIdx.x;
    if (t < B_ * 8) {
        int b = t >> 3, o = t & 7;
        float a = gab1[o];
        for (int i = 0; i < RCH; i++) a += gaw1[o * RCH + i] * gp[b * RCH + i];
        g1[b * 8 + o] = elu1(a);
    }
    __syncthreads();
    {
        int b = t >> 4, o = t & 15;
        float a = gab2[o];
        for (int i = 0; i < 8; i++) a += gaw2[o * 8 + i] * g1[b * 8 + i];
        gf[t] = a;
    }
    __syncthreads();
    {
        int b = t >> 4, o = t & 15;
        float a = afb1[o];
        for (int i = 0; i < RCH; i++) a += afw1[o * 2 * RCH + i] * gf[b * RCH + i];
        gbias[t] = a;
    }
}

// ---------- 7. 3x3 conv q -> lraw (zero pad, bias) ----------
__global__ __launch_bounds__(256) void k_conv_la(const float* __restrict__ q,
    const float* __restrict__ law, const float* __restrict__ lab, float* __restrict__ lraw)
{
    __shared__ float wl[RCH * RCH * 9];   // 2304
    for (int i = threadIdx.x; i < RCH * RCH * 9; i += 256) wl[i] = law[i];
    __syncthreads();
    int idx = blockIdx.x * 256 + threadIdx.x;      // B_*HW
    int b = idx / HW, p = idx - b * HW;
    int h = p / W_, w = p - h * W_;
    float acc[RCH];
#pragma unroll
    for (int co = 0; co < RCH; co++) acc[co] = lab[co];
    for (int ci = 0; ci < RCH; ci++) {
        const float* qb = q + ((size_t)b * RCH + ci) * HW;
#pragma unroll
        for (int kh = 0; kh < 3; kh++) {
            int hh = h + kh - 1;
            if (hh < 0 || hh >= H_) continue;
            float a0 = (w - 1 >= 0) ? qb[hh * W_ + w - 1] : 0.f;
            float a1 = qb[hh * W_ + w];
            float a2 = (w + 1 < W_) ? qb[hh * W_ + w + 1] : 0.f;
#pragma unroll
            for (int co = 0; co < RCH; co++) {
                const float* wp = &wl[(co * RCH + ci) * 9 + kh * 3];
                acc[co] += a0 * wp[0] + a1 * wp[1] + a2 * wp[2];
            }
        }
    }
#pragma unroll
    for (int co = 0; co < RCH; co++) lraw[((size_t)b * RCH + co) * HW + p] = acc[co];
}

// ---------- 8. fused: GN(lraw)+elu -> attn MLP -> sigmoid; warp km; vol ----------
__global__ __launch_bounds__(256) void k_vol(const float* __restrict__ lraw,
    const float* __restrict__ stats, const float* __restrict__ lg, const float* __restrict__ lb,
    const float* __restrict__ gbias, const float* __restrict__ afw1,
    const float* __restrict__ afw2, const float* __restrict__ afb2,
    const float* __restrict__ km, const float* __restrict__ directs, float* __restrict__ vol)
{
    __shared__ float w1[RCH * 2 * RCH];   // 512
    __shared__ float w2[D_ * RCH];        // 768
    __shared__ float b2[D_];
    for (int i = threadIdx.x; i < RCH * 2 * RCH; i += 256) w1[i] = afw1[i];
    for (int i = threadIdx.x; i < D_ * RCH; i += 256) w2[i] = afw2[i];
    if (threadIdx.x < D_) b2[threadIdx.x] = afb2[threadIdx.x];
    __syncthreads();
    int idx = blockIdx.x * 256 + threadIdx.x;      // B_*HW
    int b = idx / HW, p = idx - b * HW;
    int h = p / W_, w = p - h * W_;
    float lf[RCH];
#pragma unroll
    for (int rc = 0; rc < RCH; rc++) {
        int g = rc >> 1;
        float m = stats[(b * NG + g) * 2], is = stats[(b * NG + g) * 2 + 1];
        lf[rc] = elu1((lraw[((size_t)b * RCH + rc) * HW + p] - m) * is * lg[rc] + lb[rc]);
    }
    float hid[RCH];
#pragma unroll
    for (int o = 0; o < RCH; o++) {
        float a = gbias[b * RCH + o];
#pragma unroll
        for (int i = 0; i < RCH; i++) a += w1[o * 2 * RCH + RCH + i] * lf[i];
        hid[o] = elu1(a);
    }
    const float* kmrow = km + (size_t)b * HW + h * W_;
    float dir = directs[b];
    for (int d = 0; d < D_; d++) {
        float a = b2[d];
#pragma unroll
        for (int o = 0; o < RCH; o++) a += w2[d * RCH + o] * hid[o];
        float s = sigm(a);
        float shift = ((float)d / 160.f) * dir * (float)(W_ - 1);
        float pos = (float)w + shift;
        float x0 = floorf(pos);
        float f = pos - x0;
        float c0 = fminf(fmaxf(x0, 0.f), (float)(W_ - 1));
        float c1 = fminf(fmaxf(x0 + 1.f, 0.f), (float)(W_ - 1));
        int i0 = (int)c0, i1 = (int)c1;
        float wv = kmrow[i0] * (1.f - f) + kmrow[i1] * f;
        vol[((size_t)(b * D_ + d)) * HW + p] = wv * s;
    }
}

// ---------- 9. depthwise 3x3 + elu, 4 px/thread ----------
__global__ __launch_bounds__(256) void k_dw(const float* __restrict__ vol,
    const float* __restrict__ wgt, const float* __restrict__ bias, float* __restrict__ dwout)
{
    int idx = blockIdx.x * 256 + threadIdx.x;      // B_*D_*HW/4
    int p4 = idx % (HW / 4);
    int d  = (idx / (HW / 4)) % D_;
    int b  = idx / (D_ * HW / 4);
    int h = p4 / (W_ / 4), w = (p4 % (W_ / 4)) * 4;
    const float* vb = vol + ((size_t)(b * D_ + d)) * HW;
    float wz[9];
#pragma unroll
    for (int i = 0; i < 9; i++) wz[i] = wgt[d * 9 + i];
    float bv = bias[d];
    float acc[4] = {bv, bv, bv, bv};
#pragma unroll
    for (int r = 0; r < 3; r++) {
        int hh = h + r - 1;
        if (hh < 0 || hh >= H_) continue;
        const float* row = vb + hh * W_;
        float4 c = *(const float4*)(row + w);
        float in6[6];
        in6[0] = (w > 0) ? row[w - 1] : 0.f;
        in6[1] = c.x; in6[2] = c.y; in6[3] = c.z; in6[4] = c.w;
        in6[5] = (w + 4 < W_) ? row[w + 4] : 0.f;
#pragma unroll
        for (int j = 0; j < 4; j++)
            acc[j] += in6[j] * wz[r * 3] + in6[j + 1] * wz[r * 3 + 1] + in6[j + 2] * wz[r * 3 + 2];
    }
    float4 o;
    o.x = elu1(acc[0]); o.y = elu1(acc[1]); o.z = elu1(acc[2]); o.w = elu1(acc[3]);
    ((float4*)dwout)[idx] = o;
}

// ---------- 9b. prep: abf[b][h][322][120ci] bf16 — left channels (dw 0..31) + zero pad (dw 56..59) ----------
__global__ __launch_bounds__(256) void k_prep(const float* __restrict__ left, unsigned int* __restrict__ abf)
{
    int idx = blockIdx.x * 256 + threadIdx.x;      // B_*H_*APX = 123,648 exactly
    int px = idx % APX;
    int bh = idx / APX;
    int b = bh / H_, h = bh % H_;
    int w = px - 1;
    w = w < 0 ? -w : (w >= W_ ? 2 * W_ - 2 - w : w);
    const float* src = left + (size_t)b * C_ * HW + h * W_ + w;
    unsigned int* dst = abf + (size_t)idx * 60;
#pragma unroll
    for (int q4 = 0; q4 < 8; q4++) {
        u32x4 t;
#pragma unroll
        for (int z = 0; z < 4; z++) {
            int ci = (q4 * 4 + z) * 2;
            float f0 = src[(size_t)ci * HW];
            float f1 = src[(size_t)(ci + 1) * HW];
            t[z] = bf16rne(f0) | (bf16rne(f1) << 16);
        }
        *reinterpret_cast<u32x4*>(dst + q4 * 4) = t;
    }
    *reinterpret_cast<u32x4*>(dst + 56) = (u32x4){0u, 0u, 0u, 0u};
}

// ---------- 10. 1x1 48->48 + softmax -> norm_cost ; also writes abf dwords 32..55 ----------
// FULLY register-resident (round-3 fix: non-unrolled d-loop put cst[]/v[] in scratch ->
// 50 MB of spill traffic, occupancy 0.3%). All loops unrolled; weights via float4 LDS reads.
__global__ __launch_bounds__(256) void k_rpw(const float* __restrict__ dwin,
    const float* __restrict__ wgt, const float* __restrict__ bias,
    float* __restrict__ ncost, unsigned int* __restrict__ abf)
{
    __shared__ float wr[D_ * D_];   // 2304
    __shared__ float bs[D_];
    for (int i = threadIdx.x; i < D_ * D_; i += 256) wr[i] = wgt[i];
    if (threadIdx.x < D_) bs[threadIdx.x] = bias[threadIdx.x];
    __syncthreads();
    int idx = blockIdx.x * 256 + threadIdx.x;      // B_*HW
    int b = idx / HW, p = idx - b * HW;
    int h = p / W_, w = p - h * W_;
    float v[D_];
#pragma unroll
    for (int i = 0; i < D_; i++) v[i] = dwin[((size_t)(b * D_ + i)) * HW + p];
    float cst[D_];
    float mx = -1e30f;
#pragma unroll
    for (int d = 0; d < D_; d++) {
        float a = bs[d];
        const float4* wrow = (const float4*)&wr[d * D_];
#pragma unroll
        for (int i4 = 0; i4 < D_ / 4; i4++) {
            float4 wv = wrow[i4];
            a += wv.x * v[i4 * 4 + 0] + wv.y * v[i4 * 4 + 1]
               + wv.z * v[i4 * 4 + 2] + wv.w * v[i4 * 4 + 3];
        }
        cst[d] = a; mx = fmaxf(mx, a);
    }
    float s = 0.f;
#pragma unroll
    for (int d = 0; d < D_; d++) { float e = __expf(cst[d] - mx); cst[d] = e; s += e; }
    float inv = 1.f / s;
#pragma unroll
    for (int d = 0; d < D_; d++) {
        cst[d] *= inv;
        ncost[((size_t)(b * D_ + d)) * HW + p] = cst[d];
    }
    // pack into abf (ci 64..111 -> dwords 32..55)
    u32x4 pk[6];
#pragma unroll
    for (int q4 = 0; q4 < 6; q4++)
#pragma unroll
        for (int z = 0; z < 4; z++) {
            int d = (q4 * 4 + z) * 2;
            pk[q4][z] = bf16rne(cst[d]) | (bf16rne(cst[d + 1]) << 16);
        }
    size_t bh322 = (size_t)(b * H_ + h) * APX;
    unsigned int* dst = abf + (bh322 + (w + 1)) * 60 + 32;
#pragma unroll
    for (int q4 = 0; q4 < 6; q4++) *reinterpret_cast<u32x4*>(dst + q4 * 4) = pk[q4];
    if (w == 1 || w == W_ - 2) {
        unsigned int* dst2 = abf + (bh322 + (w == 1 ? 0 : APX - 1)) * 60 + 32;
#pragma unroll
        for (int q4 = 0; q4 < 6; q4++) *reinterpret_cast<u32x4*>(dst2 + q4 * 4) = pk[q4];
    }
}

// ---------- 11a. weight prepack for MFMA fused conv ----------
// wpack[step(36)][ct(4)][lane(64)][j(8)] bf16, step = (kh*3+kw)*4 + kblk
// B[k][n]: k = kblk*32 + (lane>>4)*8 + j (ci, 128-padded), n = ct*16 + (lane&15) (co)
__global__ __launch_bounds__(256) void k_wpack(const float* __restrict__ fw, unsigned short* __restrict__ wpack)
{
    int bi = blockIdx.x;           // 0..35
    int tap = bi >> 2, kblk = bi & 3;
    int kh = tap / 3, kw2 = tap % 3;
    int t = threadIdx.x;
    int ct = t >> 6, l = t & 63;
    int co = ct * 16 + (l & 15);
    int ci0 = kblk * 32 + ((l >> 4) & 3) * 8;
    unsigned short v[8];
#pragma unroll
    for (int j = 0; j < 8; j++) {
        int ci = ci0 + j;
        float f = (ci < 112) ? fw[((size_t)(co * 112 + ci)) * 9 + kh * 3 + kw2] : 0.f;
        v[j] = (unsigned short)bf16rne(f);
    }
    *reinterpret_cast<short8*>(wpack + ((size_t)bi * 256 + t) * 8) = *reinterpret_cast<short8*>(v);
}

// ---------- 11b. fused 3x3 conv 112->64, reflect pad, bf16 MFMA implicit GEMM ----------
// Block: 2 output rows x 64 px x 64 co. 4 waves: wave = (row, co-half).
// A staged from abf via global_load_lds: 4 planes x 66 px x 240 B, fully contiguous.
static constexpr int LROWB  = 240;           // bytes per px (120 bf16)
static constexpr int LPLANB = 66 * LROWB;    // 15840 bytes per input row
__global__ __launch_bounds__(256, 1) void k_fused_mfma(
    const unsigned int* __restrict__ abf,
    const unsigned short* __restrict__ wpack, const float* __restrict__ fb,
    float* __restrict__ fused)
{
    __shared__ __align__(16) unsigned int Atile4[15844];   // 63376 B (incl 16B overread pad)
    int bb = blockIdx.z;
    int h0 = blockIdx.y * 2;
    int w0 = blockIdx.x * 64;
    int tid = threadIdx.x;
    int wid = tid >> 6;          // wave id
    int l   = tid & 63;

    // ---- stage plane `wid` (input row h0-1+wid, reflect) ----
    {
        int hh = h0 - 1 + wid;
        hh = hh < 0 ? -hh : (hh >= H_ ? 2 * H_ - 2 - hh : hh);
        const char* gsrc = (const char*)(abf + ((size_t)(bb * H_ + hh) * APX + w0) * 60);
        char* lbase = (char*)Atile4 + wid * LPLANB;
#pragma unroll
        for (int i = 0; i < 15; i++)
            gload16(gsrc + (i * 64 + l) * 16, lbase + i * 1024);
        if (l < 30) gload16(gsrc + (960 + l) * 16, lbase + 15 * 1024);
    }
    __syncthreads();

    int row = wid >> 1;          // output row within block (0..1)
    int ch  = wid & 1;           // co half (0..1)
    int li = l & 15, lg = l >> 4;

    const short8* __restrict__ wp8 = reinterpret_cast<const short8*>(wpack);

    f32x4 acc[4][2];
    float bv0 = fb[(ch * 2 + 0) * 16 + li];
    float bv1 = fb[(ch * 2 + 1) * 16 + li];
#pragma unroll
    for (int pt = 0; pt < 4; pt++) {
        acc[pt][0] = (f32x4){bv0, bv0, bv0, bv0};
        acc[pt][1] = (f32x4){bv1, bv1, bv1, bv1};
    }

    const char* Abase = (const char*)Atile4;
#pragma unroll
    for (int kh = 0; kh < 3; kh++) {
#pragma unroll
        for (int kw2 = 0; kw2 < 3; kw2++) {
#pragma unroll
            for (int kblk = 0; kblk < 4; kblk++) {
                int step = (kh * 3 + kw2) * 4 + kblk;
                short8 b0 = wp8[step * 256 + (ch * 2 + 0) * 64 + l];
                short8 b1 = wp8[step * 256 + (ch * 2 + 1) * 64 + l];
                int rbase = (row + kh) * LPLANB + kblk * 64 + lg * 16 + (kw2 + li) * LROWB;
#pragma unroll
                for (int pt = 0; pt < 4; pt++) {
                    short8 a = *reinterpret_cast<const short8*>(Abase + rbase + pt * (16 * LROWB));
                    acc[pt][0] = __builtin_amdgcn_mfma_f32_16x16x32_bf16(a, b0, acc[pt][0], 0, 0, 0);
                    acc[pt][1] = __builtin_amdgcn_mfma_f32_16x16x32_bf16(a, b1, acc[pt][1], 0, 0, 0);
                }
            }
        }
    }

    // ---- epilogue: C row = px = pt*16 + lg*4 + reg, col = co = ct*16 + li ----
    int h = h0 + row;
#pragma unroll
    for (int j = 0; j < 2; j++) {
        int co = (ch * 2 + j) * 16 + li;
        float* ob = fused + ((size_t)(bb * C_ + co) * H_ + h) * W_ + w0 + lg * 4;
#pragma unroll
        for (int pt = 0; pt < 4; pt++) {
            *reinterpret_cast<f32x4*>(ob + pt * 16) = acc[pt][j];
        }
    }
}

// ---------- 12. SE MLP ----------
__global__ __launch_bounds__(256) void k_se(const float* __restrict__ ymean,
    const float* __restrict__ w1, const float* __restrict__ w2, float* __restrict__ scale)
{
    __shared__ float h4[B_ * 4];
    int t = threadIdx.x;
    if (t < B_ * 4) {
        int b = t >> 2, o = t & 3;
        float a = 0.f;
        for (int c = 0; c < C_; c++) a += w1[o * C_ + c] * ymean[b * C_ + c];
        h4[b * 4 + o] = fmaxf(a, 0.f);
    }
    __syncthreads();
    {
        int b = t >> 6, c = t & 63;
        float a = 0.f;
        for (int o = 0; o < 4; o++) a += w2[c * 4 + o] * h4[b * 4 + o];
        scale[t] = sigm(a);
    }
}

// ---------- 13. final: x = elu(fused * scale), float4 ----------
__global__ __launch_bounds__(256) void k_final(const float* __restrict__ fused,
    const float* __restrict__ scale, float* __restrict__ out)
{
    int idx4 = blockIdx.x * 256 + threadIdx.x;     // B_*C_*HW/4
    int bc = idx4 / (HW / 4);
    float sc = scale[bc];
    float4 v = ((const float4*)fused)[idx4];
    v.x = elu1(v.x * sc); v.y = elu1(v.y * sc);
    v.z = elu1(v.z * sc); v.w = elu1(v.w * sc);
    ((float4*)out)[idx4] = v;
}

extern "C" void kernel_launch(void* const* d_in, const int* in_sizes, int n_in,
                              void* d_out, int out_size, void* d_ws, size_t ws_size,
                              hipStream_t stream)
{
    const float* left   = (const float*)d_in[0];
    const float* right  = (const float*)d_in[1];
    const float* directs= (const float*)d_in[2];
    const float* qw     = (const float*)d_in[3];
    const float* q_g    = (const float*)d_in[4];
    const float* q_b    = (const float*)d_in[5];
    const float* kw     = (const float*)d_in[6];
    const float* k_g    = (const float*)d_in[7];
    const float* k_b    = (const float*)d_in[8];
    const float* gaw1   = (const float*)d_in[9];
    const float* gab1   = (const float*)d_in[10];
    const float* gaw2   = (const float*)d_in[11];
    const float* gab2   = (const float*)d_in[12];
    const float* law    = (const float*)d_in[13];
    const float* lab    = (const float*)d_in[14];
    const float* lag    = (const float*)d_in[15];
    const float* labb   = (const float*)d_in[16];
    const float* afw1   = (const float*)d_in[17];
    const float* afb1   = (const float*)d_in[18];
    const float* afw2   = (const float*)d_in[19];
    const float* afb2   = (const float*)d_in[20];
    const float* rdww   = (const float*)d_in[21];
    const float* rdwb   = (const float*)d_in[22];
    const float* rpww   = (const float*)d_in[23];
    const float* rpwb   = (const float*)d_in[24];
    const float* fuw    = (const float*)d_in[25];
    const float* fub    = (const float*)d_in[26];
    const float* sew1   = (const float*)d_in[27];
    const float* sew2   = (const float*)d_in[28];

    // workspace layout (floats). Peak 15,852,544 floats = 63.4 MB (same proven footprint).
    // Phase A (through k_dw):  qraw[0..1.97M) kraw[1.97..3.93M) km[3.93..4.06M) vol[4.06..9.95M) dwb[9.95..15.85M)
    // Phase B (k_prep onward): abf[0..7.42M) (over dead qraw/kraw/km/vol-start), dwb still live until k_rpw
    // Phase C (k_fused_mfma):  fused[7.42M..15.28M) (over dead vol-tail/dwb), abf still live, wpack at 15.81M
    float* ws    = (float*)d_ws;
    float* qraw  = ws + 0;
    float* kraw  = ws + 1966080;
    float* km    = ws + 3932160;
    float* vol   = ws + 4055040;
    float* dwb   = ws + 9953280;          // ends 15,851,520
    float* smal  = ws + 15851520;         // 1024 floats
    unsigned int* abf = (unsigned int*)(ws + 0);       // B*H*322*60 dwords = 7,418,880 floats
    float* fused = ws + 7418880;          // 7,864,320 -> ends 15,283,200
    float* lraw  = kraw;
    unsigned short* wpack = (unsigned short*)(ws + 15811584);  // 73,728 bf16, ends 15,848,448

    float* stQ   = smal + 0;
    float* stK   = smal + 64;
    float* stL   = smal + 128;
    float* gp    = smal + 192;
    float* gbias = smal + 256;
    float* ymean = smal + 320;
    float* scal  = smal + 576;

    float* xout  = (float*)d_out;            // 7,864,320
    float* ncost = xout + 7864320;           // 5,898,240

    k_conv_qk<<<480, 256, 0, stream>>>(left, right, qw, kw, qraw, kraw);
    k_gn_stats<<<32, 256, 0, stream>>>(qraw, stQ);
    k_gn_stats<<<32, 256, 0, stream>>>(kraw, stK);
    k_gn_apply<<<1920, 256, 0, stream>>>(qraw, stQ, q_g, q_b);
    k_km<<<480, 256, 0, stream>>>(kraw, stK, k_g, k_b, km);
    k_rowmean<<<64, 256, 0, stream>>>(qraw, gp);
    k_gfeat<<<1, 64, 0, stream>>>(gp, gaw1, gab1, gaw2, gab2, afw1, afb1, gbias);
    k_conv_la<<<480, 256, 0, stream>>>(qraw, law, lab, lraw);
    k_gn_stats<<<32, 256, 0, stream>>>(lraw, stL);
    k_vol<<<480, 256, 0, stream>>>(lraw, stL, lag, labb, gbias, afw1, afw2, afb2, km, directs, vol);
    k_dw<<<5760, 256, 0, stream>>>(vol, rdww, rdwb, dwb);
    k_prep<<<483, 256, 0, stream>>>(left, abf);
    k_rpw<<<480, 256, 0, stream>>>(dwb, rpww, rpwb, ncost, abf);
    k_wpack<<<36, 256, 0, stream>>>(fuw, wpack);
    k_fused_mfma<<<dim3(5, 48, 4), 256, 0, stream>>>(abf, wpack, fub, fused);
    k_rowmean<<<256, 256, 0, stream>>>(fused, ymean);
    k_se<<<1, 256, 0, stream>>>(ymean, sew1, sew2, scal);
    k_final<<<7680, 256, 0, stream>>>(fused, scal, xout);
}

// Round 5
// 281.557 us; speedup vs baseline: 2.7209x; 1.0148x over previous
//
#include <hip/hip_runtime.h>
#include <math.h>

// ---- problem constants ----
static constexpr int B_  = 4;
static constexpr int C_  = 64;
static constexpr int H_  = 96;
static constexpr int W_  = 320;
static constexpr int HW  = H_ * W_;          // 30720
static constexpr int RCH = 16;               // RC = C/4
static constexpr int D_  = 48;
static constexpr int NG  = 8;                // groupnorm groups
static constexpr int CPG = RCH / NG;         // 2 channels per group
static constexpr float EPS_ = 1e-5f;
static constexpr int APX = 322;              // abf padded px count (w = -1..320)

typedef __attribute__((ext_vector_type(8))) short short8;
typedef __attribute__((ext_vector_type(4))) float f32x4;
typedef __attribute__((ext_vector_type(4))) unsigned int u32x4;

__device__ __forceinline__ float elu1(float x) { return x > 0.f ? x : __expf(x) - 1.f; }
__device__ __forceinline__ float sigm(float x) { return 1.f / (1.f + __expf(-x)); }
__device__ __forceinline__ unsigned bf16rne(float f) {
    unsigned u = __builtin_bit_cast(unsigned, f);
    u += 0x7fffu + ((u >> 16) & 1u);
    return u >> 16;
}
__device__ __forceinline__ void gload16(const void* g, void* l) {
    __builtin_amdgcn_global_load_lds((const __attribute__((address_space(1))) unsigned int*)g,
                                     (__attribute__((address_space(3))) unsigned int*)l, 16, 0, 0);
}

// ---------- 0. weight repack for scalar-load convs ----------
// qwp/kwp[c][r] (c-major, 16 r contiguous); lawp[ci][tap][co] (16 co contiguous)
__global__ __launch_bounds__(256) void k_wrepack(
    const float* __restrict__ qw, const float* __restrict__ kw, const float* __restrict__ law,
    float* __restrict__ qwp, float* __restrict__ kwp, float* __restrict__ lawp)
{
    int t = threadIdx.x;
    for (int i = t; i < RCH * C_; i += 256) {
        int c = i >> 4, r = i & 15;
        qwp[i] = qw[r * C_ + c];
        kwp[i] = kw[r * C_ + c];
    }
    for (int i = t; i < RCH * RCH * 9; i += 256) {
        int co = i & 15, rest = i >> 4;       // rest = ci*9 + tap
        int ci = rest / 9, tap = rest % 9;
        lawp[i] = law[(co * RCH + ci) * 9 + tap];
    }
}

// ---------- 1. 1x1 conv: left->qraw, right->kraw. Scalar (SGPR) weights, q/k split ----------
__global__ __launch_bounds__(256) void k_conv_qk(
    const float* __restrict__ left, const float* __restrict__ right,
    const float* __restrict__ qwp, const float* __restrict__ kwp,
    float* __restrict__ qraw, float* __restrict__ kraw)
{
    int idx = blockIdx.x * 256 + threadIdx.x;      // 2*B_*HW threads
    int half = idx / (B_ * HW);                    // 0 = q (left), 1 = k (right); block-uniform
    int r0 = idx - half * (B_ * HW);
    int b = r0 / HW, p = r0 - b * HW;
    const float* src = (half ? right : left) + (size_t)b * C_ * HW + p;
    const float* wp  = half ? kwp : qwp;
    float* dst = half ? kraw : qraw;
    float acc[RCH];
#pragma unroll
    for (int r = 0; r < RCH; r++) acc[r] = 0.f;
    for (int c = 0; c < C_; c++) {
        float v = src[(size_t)c * HW];
        const float* wrow = wp + c * RCH;          // uniform -> s_load
#pragma unroll
        for (int r = 0; r < RCH; r++) acc[r] += v * wrow[r];
    }
#pragma unroll
    for (int r = 0; r < RCH; r++) dst[((size_t)b * RCH + r) * HW + p] = acc[r];
}

// ---------- 2. group-norm stats: one block per (b,g), float4 ----------
__global__ __launch_bounds__(256) void k_gn_stats(const float* __restrict__ src, float* __restrict__ stats)
{
    int b = blockIdx.x / NG, g = blockIdx.x % NG;
    const float4* base = (const float4*)(src + ((size_t)b * RCH + g * CPG) * HW);
    float s = 0.f, ss = 0.f;
    for (int i = threadIdx.x; i < CPG * HW / 4; i += 256) {
        float4 v = base[i];
        s  += v.x + v.y + v.z + v.w;
        ss += v.x * v.x + v.y * v.y + v.z * v.z + v.w * v.w;
    }
    __shared__ float rs[256], rq[256];
    rs[threadIdx.x] = s; rq[threadIdx.x] = ss; __syncthreads();
    for (int off = 128; off > 0; off >>= 1) {
        if (threadIdx.x < off) { rs[threadIdx.x] += rs[threadIdx.x + off]; rq[threadIdx.x] += rq[threadIdx.x + off]; }
        __syncthreads();
    }
    if (threadIdx.x == 0) {
        float inv = 1.f / (float)(CPG * HW);
        float m = rs[0] * inv;
        float var = rq[0] * inv - m * m;
        stats[blockIdx.x * 2 + 0] = m;
        stats[blockIdx.x * 2 + 1] = rsqrtf(var + EPS_);
    }
}

// ---------- 3. GN apply + elu, in place (for q), float4 ----------
__global__ __launch_bounds__(256) void k_gn_apply(float* __restrict__ x, const float* __restrict__ stats,
    const float* __restrict__ gam, const float* __restrict__ bet)
{
    int idx4 = blockIdx.x * 256 + threadIdx.x;     // B_*RCH*HW/4 threads
    int b = idx4 / (RCH * HW / 4);
    int rc = (idx4 / (HW / 4)) % RCH;
    int g = rc >> 1;
    float m = stats[(b * NG + g) * 2], is = stats[(b * NG + g) * 2 + 1];
    float ga = gam[rc] * is, be = bet[rc] - m * is * gam[rc];
    float4 v = ((const float4*)x)[idx4];
    v.x = elu1(v.x * ga + be); v.y = elu1(v.y * ga + be);
    v.z = elu1(v.z * ga + be); v.w = elu1(v.w * ga + be);
    ((float4*)x)[idx4] = v;
}

// ---------- 4. km = mean over channels of elu(GN(kraw)) ----------
__global__ __launch_bounds__(256) void k_km(const float* __restrict__ kraw, const float* __restrict__ stats,
    const float* __restrict__ gam, const float* __restrict__ bet, float* __restrict__ km)
{
    int idx = blockIdx.x * 256 + threadIdx.x;      // B_*HW
    int b = idx / HW, p = idx - b * HW;
    float s = 0.f;
#pragma unroll
    for (int rc = 0; rc < RCH; rc++) {
        int g = rc >> 1;
        float m = stats[(b * NG + g) * 2], is = stats[(b * NG + g) * 2 + 1];
        float v = (kraw[((size_t)b * RCH + rc) * HW + p] - m) * is * gam[rc] + bet[rc];
        s += elu1(v);
    }
    km[idx] = s * (1.f / (float)RCH);
}

// ---------- 5. per-row mean over HW (used for gp and ymean), float4 ----------
__global__ __launch_bounds__(256) void k_rowmean(const float* __restrict__ src, float* __restrict__ out)
{
    const float4* base = (const float4*)(src + (size_t)blockIdx.x * HW);
    float s = 0.f;
    for (int p = threadIdx.x; p < HW / 4; p += 256) {
        float4 v = base[p];
        s += v.x + v.y + v.z + v.w;
    }
    __shared__ float red[256];
    red[threadIdx.x] = s; __syncthreads();
    for (int off = 128; off > 0; off >>= 1) {
        if (threadIdx.x < off) red[threadIdx.x] += red[threadIdx.x + off];
        __syncthreads();
    }
    if (threadIdx.x == 0) out[blockIdx.x] = red[0] * (1.f / (float)HW);
}

// ---------- 6. gfeat MLP + fold into attn-hidden bias: gbias[b,o] ----------
__global__ __launch_bounds__(64) void k_gfeat(const float* __restrict__ gp,
    const float* __restrict__ gaw1, const float* __restrict__ gab1,
    const float* __restrict__ gaw2, const float* __restrict__ gab2,
    const float* __restrict__ afw1, const float* __restrict__ afb1,
    float* __restrict__ gbias)
{
    __shared__ float g1[B_ * 8], gf[B_ * RCH];
    int t = threadIdx.x;
    if (t < B_ * 8) {
        int b = t >> 3, o = t & 7;
        float a = gab1[o];
        for (int i = 0; i < RCH; i++) a += gaw1[o * RCH + i] * gp[b * RCH + i];
        g1[b * 8 + o] = elu1(a);
    }
    __syncthreads();
    {
        int b = t >> 4, o = t & 15;
        float a = gab2[o];
        for (int i = 0; i < 8; i++) a += gaw2[o * 8 + i] * g1[b * 8 + i];
        gf[t] = a;
    }
    __syncthreads();
    {
        int b = t >> 4, o = t & 15;
        float a = afb1[o];
        for (int i = 0; i < RCH; i++) a += afw1[o * 2 * RCH + i] * gf[b * RCH + i];
        gbias[t] = a;
    }
}

// ---------- 7. 3x3 conv q -> lraw (zero pad, bias). Scalar (SGPR) weights ----------
__global__ __launch_bounds__(256) void k_conv_la(const float* __restrict__ q,
    const float* __restrict__ lawp, const float* __restrict__ lab, float* __restrict__ lraw)
{
    int idx = blockIdx.x * 256 + threadIdx.x;      // B_*HW
    int b = idx / HW, p = idx - b * HW;
    int h = p / W_, w = p - h * W_;
    float acc[RCH];
#pragma unroll
    for (int co = 0; co < RCH; co++) acc[co] = lab[co];
    for (int ci = 0; ci < RCH; ci++) {
        const float* qb = q + ((size_t)b * RCH + ci) * HW;
#pragma unroll
        for (int kh = 0; kh < 3; kh++) {
            int hh = h + kh - 1;
            if (hh < 0 || hh >= H_) continue;
            float a0 = (w - 1 >= 0) ? qb[hh * W_ + w - 1] : 0.f;
            float a1 = qb[hh * W_ + w];
            float a2 = (w + 1 < W_) ? qb[hh * W_ + w + 1] : 0.f;
            const float* wp0 = lawp + (ci * 9 + kh * 3) * RCH;   // uniform -> s_load
#pragma unroll
            for (int co = 0; co < RCH; co++)
                acc[co] += a0 * wp0[co] + a1 * wp0[RCH + co] + a2 * wp0[2 * RCH + co];
        }
    }
#pragma unroll
    for (int co = 0; co < RCH; co++) lraw[((size_t)b * RCH + co) * HW + p] = acc[co];
}

// ---------- 8. fused: GN(lraw)+elu -> attn MLP -> sigmoid; warp km; vol ----------
__global__ __launch_bounds__(256) void k_vol(const float* __restrict__ lraw,
    const float* __restrict__ stats, const float* __restrict__ lg, const float* __restrict__ lb,
    const float* __restrict__ gbias, const float* __restrict__ afw1,
    const float* __restrict__ afw2, const float* __restrict__ afb2,
    const float* __restrict__ km, const float* __restrict__ directs, float* __restrict__ vol)
{
    __shared__ float w1[RCH * 2 * RCH];   // 512
    __shared__ float w2[D_ * RCH];        // 768
    __shared__ float b2[D_];
    for (int i = threadIdx.x; i < RCH * 2 * RCH; i += 256) w1[i] = afw1[i];
    for (int i = threadIdx.x; i < D_ * RCH; i += 256) w2[i] = afw2[i];
    if (threadIdx.x < D_) b2[threadIdx.x] = afb2[threadIdx.x];
    __syncthreads();
    int idx = blockIdx.x * 256 + threadIdx.x;      // B_*HW
    int b = idx / HW, p = idx - b * HW;
    int h = p / W_, w = p - h * W_;
    float lf[RCH];
#pragma unroll
    for (int rc = 0; rc < RCH; rc++) {
        int g = rc >> 1;
        float m = stats[(b * NG + g) * 2], is = stats[(b * NG + g) * 2 + 1];
        lf[rc] = elu1((lraw[((size_t)b * RCH + rc) * HW + p] - m) * is * lg[rc] + lb[rc]);
    }
    float hid[RCH];
#pragma unroll
    for (int o = 0; o < RCH; o++) {
        float a = gbias[b * RCH + o];
#pragma unroll
        for (int i = 0; i < RCH; i++) a += w1[o * 2 * RCH + RCH + i] * lf[i];
        hid[o] = elu1(a);
    }
    const float* kmrow = km + (size_t)b * HW + h * W_;
    float dir = directs[b];
    for (int d = 0; d < D_; d++) {
        float a = b2[d];
#pragma unroll
        for (int o = 0; o < RCH; o++) a += w2[d * RCH + o] * hid[o];
        float s = sigm(a);
        float shift = ((float)d / 160.f) * dir * (float)(W_ - 1);
        float pos = (float)w + shift;
        float x0 = floorf(pos);
        float f = pos - x0;
        float c0 = fminf(fmaxf(x0, 0.f), (float)(W_ - 1));
        float c1 = fminf(fmaxf(x0 + 1.f, 0.f), (float)(W_ - 1));
        int i0 = (int)c0, i1 = (int)c1;
        float wv = kmrow[i0] * (1.f - f) + kmrow[i1] * f;
        vol[((size_t)(b * D_ + d)) * HW + p] = wv * s;
    }
}

// ---------- 9. depthwise 3x3 + elu, 4 px/thread ----------
__global__ __launch_bounds__(256) void k_dw(const float* __restrict__ vol,
    const float* __restrict__ wgt, const float* __restrict__ bias, float* __restrict__ dwout)
{
    int idx = blockIdx.x * 256 + threadIdx.x;      // B_*D_*HW/4
    int p4 = idx % (HW / 4);
    int d  = (idx / (HW / 4)) % D_;
    int b  = idx / (D_ * HW / 4);
    int h = p4 / (W_ / 4), w = (p4 % (W_ / 4)) * 4;
    const float* vb = vol + ((size_t)(b * D_ + d)) * HW;
    float wz[9];
#pragma unroll
    for (int i = 0; i < 9; i++) wz[i] = wgt[d * 9 + i];
    float bv = bias[d];
    float acc[4] = {bv, bv, bv, bv};
#pragma unroll
    for (int r = 0; r < 3; r++) {
        int hh = h + r - 1;
        if (hh < 0 || hh >= H_) continue;
        const float* row = vb + hh * W_;
        float4 c = *(const float4*)(row + w);
        float in6[6];
        in6[0] = (w > 0) ? row[w - 1] : 0.f;
        in6[1] = c.x; in6[2] = c.y; in6[3] = c.z; in6[4] = c.w;
        in6[5] = (w + 4 < W_) ? row[w + 4] : 0.f;
#pragma unroll
        for (int j = 0; j < 4; j++)
            acc[j] += in6[j] * wz[r * 3] + in6[j + 1] * wz[r * 3 + 1] + in6[j + 2] * wz[r * 3 + 2];
    }
    float4 o;
    o.x = elu1(acc[0]); o.y = elu1(acc[1]); o.z = elu1(acc[2]); o.w = elu1(acc[3]);
    ((float4*)dwout)[idx] = o;
}

// ---------- 9b. prep: abf[b][h][322][120ci] bf16 — left channels (dw 0..31) + zero pad (dw 56..59) ----------
__global__ __launch_bounds__(256) void k_prep(const float* __restrict__ left, unsigned int* __restrict__ abf)
{
    int idx = blockIdx.x * 256 + threadIdx.x;      // B_*H_*APX = 123,648 exactly
    int px = idx % APX;
    int bh = idx / APX;
    int b = bh / H_, h = bh % H_;
    int w = px - 1;
    w = w < 0 ? -w : (w >= W_ ? 2 * W_ - 2 - w : w);
    const float* src = left + (size_t)b * C_ * HW + h * W_ + w;
    unsigned int* dst = abf + (size_t)idx * 60;
#pragma unroll
    for (int q4 = 0; q4 < 8; q4++) {
        u32x4 t;
#pragma unroll
        for (int z = 0; z < 4; z++) {
            int ci = (q4 * 4 + z) * 2;
            float f0 = src[(size_t)ci * HW];
            float f1 = src[(size_t)(ci + 1) * HW];
            t[z] = bf16rne(f0) | (bf16rne(f1) << 16);
        }
        *reinterpret_cast<u32x4*>(dst + q4 * 4) = t;
    }
    *reinterpret_cast<u32x4*>(dst + 56) = (u32x4){0u, 0u, 0u, 0u};
}

// ---------- 10. 1x1 48->48 + softmax -> norm_cost ; also writes abf dwords 32..55 ----------
// FULLY register-resident; weights via float4 LDS reads (uniform -> broadcast).
__global__ __launch_bounds__(256) void k_rpw(const float* __restrict__ dwin,
    const float* __restrict__ wgt, const float* __restrict__ bias,
    float* __restrict__ ncost, unsigned int* __restrict__ abf)
{
    __shared__ float wr[D_ * D_];   // 2304
    __shared__ float bs[D_];
    for (int i = threadIdx.x; i < D_ * D_; i += 256) wr[i] = wgt[i];
    if (threadIdx.x < D_) bs[threadIdx.x] = bias[threadIdx.x];
    __syncthreads();
    int idx = blockIdx.x * 256 + threadIdx.x;      // B_*HW
    int b = idx / HW, p = idx - b * HW;
    int h = p / W_, w = p - h * W_;
    float v[D_];
#pragma unroll
    for (int i = 0; i < D_; i++) v[i] = dwin[((size_t)(b * D_ + i)) * HW + p];
    float cst[D_];
    float mx = -1e30f;
#pragma unroll
    for (int d = 0; d < D_; d++) {
        float a = bs[d];
        const float4* wrow = (const float4*)&wr[d * D_];
#pragma unroll
        for (int i4 = 0; i4 < D_ / 4; i4++) {
            float4 wv = wrow[i4];
            a += wv.x * v[i4 * 4 + 0] + wv.y * v[i4 * 4 + 1]
               + wv.z * v[i4 * 4 + 2] + wv.w * v[i4 * 4 + 3];
        }
        cst[d] = a; mx = fmaxf(mx, a);
    }
    float s = 0.f;
#pragma unroll
    for (int d = 0; d < D_; d++) { float e = __expf(cst[d] - mx); cst[d] = e; s += e; }
    float inv = 1.f / s;
#pragma unroll
    for (int d = 0; d < D_; d++) {
        cst[d] *= inv;
        ncost[((size_t)(b * D_ + d)) * HW + p] = cst[d];
    }
    // pack into abf (ci 64..111 -> dwords 32..55)
    u32x4 pk[6];
#pragma unroll
    for (int q4 = 0; q4 < 6; q4++)
#pragma unroll
        for (int z = 0; z < 4; z++) {
            int d = (q4 * 4 + z) * 2;
            pk[q4][z] = bf16rne(cst[d]) | (bf16rne(cst[d + 1]) << 16);
        }
    size_t bh322 = (size_t)(b * H_ + h) * APX;
    unsigned int* dst = abf + (bh322 + (w + 1)) * 60 + 32;
#pragma unroll
    for (int q4 = 0; q4 < 6; q4++) *reinterpret_cast<u32x4*>(dst + q4 * 4) = pk[q4];
    if (w == 1 || w == W_ - 2) {
        unsigned int* dst2 = abf + (bh322 + (w == 1 ? 0 : APX - 1)) * 60 + 32;
#pragma unroll
        for (int q4 = 0; q4 < 6; q4++) *reinterpret_cast<u32x4*>(dst2 + q4 * 4) = pk[q4];
    }
}

// ---------- 11a. weight prepack for MFMA fused conv ----------
__global__ __launch_bounds__(256) void k_wpack(const float* __restrict__ fw, unsigned short* __restrict__ wpack)
{
    int bi = blockIdx.x;           // 0..35
    int tap = bi >> 2, kblk = bi & 3;
    int kh = tap / 3, kw2 = tap % 3;
    int t = threadIdx.x;
    int ct = t >> 6, l = t & 63;
    int co = ct * 16 + (l & 15);
    int ci0 = kblk * 32 + ((l >> 4) & 3) * 8;
    unsigned short v[8];
#pragma unroll
    for (int j = 0; j < 8; j++) {
        int ci = ci0 + j;
        float f = (ci < 112) ? fw[((size_t)(co * 112 + ci)) * 9 + kh * 3 + kw2] : 0.f;
        v[j] = (unsigned short)bf16rne(f);
    }
    *reinterpret_cast<short8*>(wpack + ((size_t)bi * 256 + t) * 8) = *reinterpret_cast<short8*>(v);
}

// ---------- 11b. fused 3x3 conv 112->64, reflect pad, bf16 MFMA implicit GEMM ----------
static constexpr int LROWB  = 240;           // bytes per px (120 bf16)
static constexpr int LPLANB = 66 * LROWB;    // 15840 bytes per input row
__global__ __launch_bounds__(256, 1) void k_fused_mfma(
    const unsigned int* __restrict__ abf,
    const unsigned short* __restrict__ wpack, const float* __restrict__ fb,
    float* __restrict__ fused)
{
    __shared__ __align__(16) unsigned int Atile4[15844];   // 63376 B (incl 16B overread pad)
    int bb = blockIdx.z;
    int h0 = blockIdx.y * 2;
    int w0 = blockIdx.x * 64;
    int tid = threadIdx.x;
    int wid = tid >> 6;          // wave id
    int l   = tid & 63;

    // ---- stage plane `wid` (input row h0-1+wid, reflect) ----
    {
        int hh = h0 - 1 + wid;
        hh = hh < 0 ? -hh : (hh >= H_ ? 2 * H_ - 2 - hh : hh);
        const char* gsrc = (const char*)(abf + ((size_t)(bb * H_ + hh) * APX + w0) * 60);
        char* lbase = (char*)Atile4 + wid * LPLANB;
#pragma unroll
        for (int i = 0; i < 15; i++)
            gload16(gsrc + (i * 64 + l) * 16, lbase + i * 1024);
        if (l < 30) gload16(gsrc + (960 + l) * 16, lbase + 15 * 1024);
    }
    __syncthreads();

    int row = wid >> 1;          // output row within block (0..1)
    int ch  = wid & 1;           // co half (0..1)
    int li = l & 15, lg = l >> 4;

    const short8* __restrict__ wp8 = reinterpret_cast<const short8*>(wpack);

    f32x4 acc[4][2];
    float bv0 = fb[(ch * 2 + 0) * 16 + li];
    float bv1 = fb[(ch * 2 + 1) * 16 + li];
#pragma unroll
    for (int pt = 0; pt < 4; pt++) {
        acc[pt][0] = (f32x4){bv0, bv0, bv0, bv0};
        acc[pt][1] = (f32x4){bv1, bv1, bv1, bv1};
    }

    const char* Abase = (const char*)Atile4;
#pragma unroll
    for (int kh = 0; kh < 3; kh++) {
#pragma unroll
        for (int kw2 = 0; kw2 < 3; kw2++) {
#pragma unroll
            for (int kblk = 0; kblk < 4; kblk++) {
                int step = (kh * 3 + kw2) * 4 + kblk;
                short8 b0 = wp8[step * 256 + (ch * 2 + 0) * 64 + l];
                short8 b1 = wp8[step * 256 + (ch * 2 + 1) * 64 + l];
                int rbase = (row + kh) * LPLANB + kblk * 64 + lg * 16 + (kw2 + li) * LROWB;
#pragma unroll
                for (int pt = 0; pt < 4; pt++) {
                    short8 a = *reinterpret_cast<const short8*>(Abase + rbase + pt * (16 * LROWB));
                    acc[pt][0] = __builtin_amdgcn_mfma_f32_16x16x32_bf16(a, b0, acc[pt][0], 0, 0, 0);
                    acc[pt][1] = __builtin_amdgcn_mfma_f32_16x16x32_bf16(a, b1, acc[pt][1], 0, 0, 0);
                }
            }
        }
    }

    // ---- epilogue: C row = px = pt*16 + lg*4 + reg, col = co = ct*16 + li ----
    int h = h0 + row;
#pragma unroll
    for (int j = 0; j < 2; j++) {
        int co = (ch * 2 + j) * 16 + li;
        float* ob = fused + ((size_t)(bb * C_ + co) * H_ + h) * W_ + w0 + lg * 4;
#pragma unroll
        for (int pt = 0; pt < 4; pt++) {
            *reinterpret_cast<f32x4*>(ob + pt * 16) = acc[pt][j];
        }
    }
}

// ---------- 12. SE MLP ----------
__global__ __launch_bounds__(256) void k_se(const float* __restrict__ ymean,
    const float* __restrict__ w1, const float* __restrict__ w2, float* __restrict__ scale)
{
    __shared__ float h4[B_ * 4];
    int t = threadIdx.x;
    if (t < B_ * 4) {
        int b = t >> 2, o = t & 3;
        float a = 0.f;
        for (int c = 0; c < C_; c++) a += w1[o * C_ + c] * ymean[b * C_ + c];
        h4[b * 4 + o] = fmaxf(a, 0.f);
    }
    __syncthreads();
    {
        int b = t >> 6, c = t & 63;
        float a = 0.f;
        for (int o = 0; o < 4; o++) a += w2[c * 4 + o] * h4[b * 4 + o];
        scale[t] = sigm(a);
    }
}

// ---------- 13. final: x = elu(fused * scale), float4 ----------
__global__ __launch_bounds__(256) void k_final(const float* __restrict__ fused,
    const float* __restrict__ scale, float* __restrict__ out)
{
    int idx4 = blockIdx.x * 256 + threadIdx.x;     // B_*C_*HW/4
    int bc = idx4 / (HW / 4);
    float sc = scale[bc];
    float4 v = ((const float4*)fused)[idx4];
    v.x = elu1(v.x * sc); v.y = elu1(v.y * sc);
    v.z = elu1(v.z * sc); v.w = elu1(v.w * sc);
    ((float4*)out)[idx4] = v;
}

extern "C" void kernel_launch(void* const* d_in, const int* in_sizes, int n_in,
                              void* d_out, int out_size, void* d_ws, size_t ws_size,
                              hipStream_t stream)
{
    const float* left   = (const float*)d_in[0];
    const float* right  = (const float*)d_in[1];
    const float* directs= (const float*)d_in[2];
    const float* qw     = (const float*)d_in[3];
    const float* q_g    = (const float*)d_in[4];
    const float* q_b    = (const float*)d_in[5];
    const float* kw     = (const float*)d_in[6];
    const float* k_g    = (const float*)d_in[7];
    const float* k_b    = (const float*)d_in[8];
    const float* gaw1   = (const float*)d_in[9];
    const float* gab1   = (const float*)d_in[10];
    const float* gaw2   = (const float*)d_in[11];
    const float* gab2   = (const float*)d_in[12];
    const float* law    = (const float*)d_in[13];
    const float* lab    = (const float*)d_in[14];
    const float* lag    = (const float*)d_in[15];
    const float* labb   = (const float*)d_in[16];
    const float* afw1   = (const float*)d_in[17];
    const float* afb1   = (const float*)d_in[18];
    const float* afw2   = (const float*)d_in[19];
    const float* afb2   = (const float*)d_in[20];
    const float* rdww   = (const float*)d_in[21];
    const float* rdwb   = (const float*)d_in[22];
    const float* rpww   = (const float*)d_in[23];
    const float* rpwb   = (const float*)d_in[24];
    const float* fuw    = (const float*)d_in[25];
    const float* fub    = (const float*)d_in[26];
    const float* sew1   = (const float*)d_in[27];
    const float* sew2   = (const float*)d_in[28];

    // workspace layout (floats). Peak 15,852,544 floats = 63.4 MB (same proven footprint).
    // Phase A (through k_dw):  qraw[0..1.97M) kraw[1.97..3.93M) km[3.93..4.06M) vol[4.06..9.95M) dwb[9.95..15.85M)
    //   + repacked conv weights (qwp/kwp/lawp, 4352 floats) at dwb start — dead before k_dw writes dwb.
    // Phase B (k_prep onward): abf[0..7.42M), dwb live until k_rpw
    // Phase C (k_fused_mfma):  fused[7.42M..15.28M), abf live, wpack at 15.81M
    float* ws    = (float*)d_ws;
    float* qraw  = ws + 0;
    float* kraw  = ws + 1966080;
    float* km    = ws + 3932160;
    float* vol   = ws + 4055040;
    float* dwb   = ws + 9953280;          // ends 15,851,520
    float* smal  = ws + 15851520;         // 1024 floats
    unsigned int* abf = (unsigned int*)(ws + 0);       // B*H*322*60 dwords = 7,418,880 floats
    float* fused = ws + 7418880;          // 7,864,320 -> ends 15,283,200
    float* lraw  = kraw;
    unsigned short* wpack = (unsigned short*)(ws + 15811584);  // 73,728 bf16, ends 15,848,448

    // repacked conv weights carved from dwb start (dead by the time k_dw writes dwb)
    float* qwp   = dwb + 0;               // 1024
    float* kwp   = dwb + 1024;            // 1024
    float* lawp  = dwb + 2048;            // 2304 (ends dwb+4352)

    float* stQ   = smal + 0;
    float* stK   = smal + 64;
    float* stL   = smal + 128;
    float* gp    = smal + 192;
    float* gbias = smal + 256;
    float* ymean = smal + 320;
    float* scal  = smal + 576;

    float* xout  = (float*)d_out;            // 7,864,320
    float* ncost = xout + 7864320;           // 5,898,240

    k_wrepack<<<1, 256, 0, stream>>>(qw, kw, law, qwp, kwp, lawp);
    k_conv_qk<<<960, 256, 0, stream>>>(left, right, qwp, kwp, qraw, kraw);
    k_gn_stats<<<32, 256, 0, stream>>>(qraw, stQ);
    k_gn_stats<<<32, 256, 0, stream>>>(kraw, stK);
    k_gn_apply<<<1920, 256, 0, stream>>>(qraw, stQ, q_g, q_b);
    k_km<<<480, 256, 0, stream>>>(kraw, stK, k_g, k_b, km);
    k_rowmean<<<64, 256, 0, stream>>>(qraw, gp);
    k_gfeat<<<1, 64, 0, stream>>>(gp, gaw1, gab1, gaw2, gab2, afw1, afb1, gbias);
    k_conv_la<<<480, 256, 0, stream>>>(qraw, lawp, lab, lraw);
    k_gn_stats<<<32, 256, 0, stream>>>(lraw, stL);
    k_vol<<<480, 256, 0, stream>>>(lraw, stL, lag, labb, gbias, afw1, afw2, afb2, km, directs, vol);
    k_dw<<<5760, 256, 0, stream>>>(vol, rdww, rdwb, dwb);
    k_prep<<<483, 256, 0, stream>>>(left, abf);
    k_rpw<<<480, 256, 0, stream>>>(dwb, rpww, rpwb, ncost, abf);
    k_wpack<<<36, 256, 0, stream>>>(fuw, wpack);
    k_fused_mfma<<<dim3(5, 48, 4), 256, 0, stream>>>(abf, wpack, fub, fused);
    k_rowmean<<<256, 256, 0, stream>>>(fused, ymean);
    k_se<<<1, 256, 0, stream>>>(ymean, sew1, sew2, scal);
    k_final<<<7680, 256, 0, stream>>>(fused, scal, xout);
}

// Round 6
// 272.491 us; speedup vs baseline: 2.8114x; 1.0333x over previous
//
#include <hip/hip_runtime.h>
#include <math.h>

// ---- problem constants ----
static constexpr int B_  = 4;
static constexpr int C_  = 64;
static constexpr int H_  = 96;
static constexpr int W_  = 320;
static constexpr int HW  = H_ * W_;          // 30720
static constexpr int RCH = 16;               // RC = C/4
static constexpr int D_  = 48;
static constexpr int NG  = 8;                // groupnorm groups
static constexpr int CPG = RCH / NG;         // 2 channels per group
static constexpr float EPS_ = 1e-5f;
static constexpr int APX = 322;              // abf padded px count (w = -1..320)

typedef __attribute__((ext_vector_type(8))) short short8;
typedef __attribute__((ext_vector_type(4))) float f32x4;
typedef __attribute__((ext_vector_type(4))) unsigned int u32x4;

__device__ __forceinline__ float elu1(float x) { return x > 0.f ? x : __expf(x) - 1.f; }
__device__ __forceinline__ float sigm(float x) { return 1.f / (1.f + __expf(-x)); }
__device__ __forceinline__ unsigned bf16rne(float f) {
    unsigned u = __builtin_bit_cast(unsigned, f);
    u += 0x7fffu + ((u >> 16) & 1u);
    return u >> 16;
}
__device__ __forceinline__ void gload16(const void* g, void* l) {
    __builtin_amdgcn_global_load_lds((const __attribute__((address_space(1))) unsigned int*)g,
                                     (__attribute__((address_space(3))) unsigned int*)l, 16, 0, 0);
}

// ---------- 0. weight repack for scalar-load convs ----------
// qwp/kwp[c][r] (c-major, 16 r contiguous); lawp[ci][tap][co] (16 co contiguous)
__global__ __launch_bounds__(256) void k_wrepack(
    const float* __restrict__ qw, const float* __restrict__ kw, const float* __restrict__ law,
    float* __restrict__ qwp, float* __restrict__ kwp, float* __restrict__ lawp)
{
    int t = threadIdx.x;
    for (int i = t; i < RCH * C_; i += 256) {
        int c = i >> 4, r = i & 15;
        qwp[i] = qw[r * C_ + c];
        kwp[i] = kw[r * C_ + c];
    }
    for (int i = t; i < RCH * RCH * 9; i += 256) {
        int co = i & 15, rest = i >> 4;       // rest = ci*9 + tap
        int ci = rest / 9, tap = rest % 9;
        lawp[i] = law[(co * RCH + ci) * 9 + tap];
    }
}

// ---------- 1. 1x1 conv: left->qraw, right->kraw. SGPR weights, 2px/thread, full unroll ----------
__global__ __launch_bounds__(256) void k_conv_qk(
    const float* __restrict__ left, const float* __restrict__ right,
    const float* __restrict__ qwp, const float* __restrict__ kwp,
    float* __restrict__ qraw, float* __restrict__ kraw)
{
    int idx = blockIdx.x * 256 + threadIdx.x;      // 480*256 = B_*HW threads (2 px each)
    int half = idx / (B_ * HW / 2);                // 0 = q (left), 1 = k (right); block-uniform
    int r0 = idx - half * (B_ * HW / 2);
    int b = r0 / (HW / 2), p2 = r0 - b * (HW / 2);
    int p = p2 * 2;
    const float* src = (half ? right : left) + (size_t)b * C_ * HW + p;
    const float* wp  = half ? kwp : qwp;
    float* dst = (half ? kraw : qraw) + (size_t)b * RCH * HW + p;
    float2 acc[RCH];
#pragma unroll
    for (int r = 0; r < RCH; r++) acc[r] = make_float2(0.f, 0.f);
#pragma unroll
    for (int c = 0; c < C_; c++) {                 // fully unrolled: 64 independent float2 loads
        float2 v = *reinterpret_cast<const float2*>(src + (size_t)c * HW);
        const float* wrow = wp + c * RCH;          // uniform -> s_load operands
#pragma unroll
        for (int r = 0; r < RCH; r++) {
            acc[r].x += v.x * wrow[r];
            acc[r].y += v.y * wrow[r];
        }
    }
#pragma unroll
    for (int r = 0; r < RCH; r++)
        *reinterpret_cast<float2*>(dst + (size_t)r * HW) = acc[r];
}

// ---------- 2. group-norm stats: one block per (b,g), float4 ----------
__global__ __launch_bounds__(256) void k_gn_stats(const float* __restrict__ src, float* __restrict__ stats)
{
    int b = blockIdx.x / NG, g = blockIdx.x % NG;
    const float4* base = (const float4*)(src + ((size_t)b * RCH + g * CPG) * HW);
    float s = 0.f, ss = 0.f;
    for (int i = threadIdx.x; i < CPG * HW / 4; i += 256) {
        float4 v = base[i];
        s  += v.x + v.y + v.z + v.w;
        ss += v.x * v.x + v.y * v.y + v.z * v.z + v.w * v.w;
    }
    __shared__ float rs[256], rq[256];
    rs[threadIdx.x] = s; rq[threadIdx.x] = ss; __syncthreads();
    for (int off = 128; off > 0; off >>= 1) {
        if (threadIdx.x < off) { rs[threadIdx.x] += rs[threadIdx.x + off]; rq[threadIdx.x] += rq[threadIdx.x + off]; }
        __syncthreads();
    }
    if (threadIdx.x == 0) {
        float inv = 1.f / (float)(CPG * HW);
        float m = rs[0] * inv;
        float var = rq[0] * inv - m * m;
        stats[blockIdx.x * 2 + 0] = m;
        stats[blockIdx.x * 2 + 1] = rsqrtf(var + EPS_);
    }
}

// ---------- 3. GN apply + elu, in place (for q), float4 ----------
__global__ __launch_bounds__(256) void k_gn_apply(float* __restrict__ x, const float* __restrict__ stats,
    const float* __restrict__ gam, const float* __restrict__ bet)
{
    int idx4 = blockIdx.x * 256 + threadIdx.x;     // B_*RCH*HW/4 threads
    int b = idx4 / (RCH * HW / 4);
    int rc = (idx4 / (HW / 4)) % RCH;
    int g = rc >> 1;
    float m = stats[(b * NG + g) * 2], is = stats[(b * NG + g) * 2 + 1];
    float ga = gam[rc] * is, be = bet[rc] - m * is * gam[rc];
    float4 v = ((const float4*)x)[idx4];
    v.x = elu1(v.x * ga + be); v.y = elu1(v.y * ga + be);
    v.z = elu1(v.z * ga + be); v.w = elu1(v.w * ga + be);
    ((float4*)x)[idx4] = v;
}

// ---------- 4. km = mean over channels of elu(GN(kraw)) ----------
__global__ __launch_bounds__(256) void k_km(const float* __restrict__ kraw, const float* __restrict__ stats,
    const float* __restrict__ gam, const float* __restrict__ bet, float* __restrict__ km)
{
    int idx = blockIdx.x * 256 + threadIdx.x;      // B_*HW
    int b = idx / HW, p = idx - b * HW;
    float s = 0.f;
#pragma unroll
    for (int rc = 0; rc < RCH; rc++) {
        int g = rc >> 1;
        float m = stats[(b * NG + g) * 2], is = stats[(b * NG + g) * 2 + 1];
        float v = (kraw[((size_t)b * RCH + rc) * HW + p] - m) * is * gam[rc] + bet[rc];
        s += elu1(v);
    }
    km[idx] = s * (1.f / (float)RCH);
}

// ---------- 5. per-row mean over HW (used for gp and ymean), float4 ----------
__global__ __launch_bounds__(256) void k_rowmean(const float* __restrict__ src, float* __restrict__ out)
{
    const float4* base = (const float4*)(src + (size_t)blockIdx.x * HW);
    float s = 0.f;
    for (int p = threadIdx.x; p < HW / 4; p += 256) {
        float4 v = base[p];
        s += v.x + v.y + v.z + v.w;
    }
    __shared__ float red[256];
    red[threadIdx.x] = s; __syncthreads();
    for (int off = 128; off > 0; off >>= 1) {
        if (threadIdx.x < off) red[threadIdx.x] += red[threadIdx.x + off];
        __syncthreads();
    }
    if (threadIdx.x == 0) out[blockIdx.x] = red[0] * (1.f / (float)HW);
}

// ---------- 6. gfeat MLP + fold into attn-hidden bias: gbias[b,o] ----------
__global__ __launch_bounds__(64) void k_gfeat(const float* __restrict__ gp,
    const float* __restrict__ gaw1, const float* __restrict__ gab1,
    const float* __restrict__ gaw2, const float* __restrict__ gab2,
    const float* __restrict__ afw1, const float* __restrict__ afb1,
    float* __restrict__ gbias)
{
    __shared__ float g1[B_ * 8], gf[B_ * RCH];
    int t = threadIdx.x;
    if (t < B_ * 8) {
        int b = t >> 3, o = t & 7;
        float a = gab1[o];
        for (int i = 0; i < RCH; i++) a += gaw1[o * RCH + i] * gp[b * RCH + i];
        g1[b * 8 + o] = elu1(a);
    }
    __syncthreads();
    {
        int b = t >> 4, o = t & 15;
        float a = gab2[o];
        for (int i = 0; i < 8; i++) a += gaw2[o * 8 + i] * g1[b * 8 + i];
        gf[t] = a;
    }
    __syncthreads();
    {
        int b = t >> 4, o = t & 15;
        float a = afb1[o];
        for (int i = 0; i < RCH; i++) a += afw1[o * 2 * RCH + i] * gf[b * RCH + i];
        gbias[t] = a;
    }
}

// ---------- 7. 3x3 conv q -> lraw (zero pad, bias). SGPR weights, full unroll ----------
__global__ __launch_bounds__(256) void k_conv_la(const float* __restrict__ q,
    const float* __restrict__ lawp, const float* __restrict__ lab, float* __restrict__ lraw)
{
    int idx = blockIdx.x * 256 + threadIdx.x;      // B_*HW
    int b = idx / HW, p = idx - b * HW;
    int h = p / W_, w = p - h * W_;
    float acc[RCH];
#pragma unroll
    for (int co = 0; co < RCH; co++) acc[co] = lab[co];
#pragma unroll
    for (int ci = 0; ci < RCH; ci++) {             // fully unrolled: loads pipeline across ci
        const float* qb = q + ((size_t)b * RCH + ci) * HW;
#pragma unroll
        for (int kh = 0; kh < 3; kh++) {
            int hh = h + kh - 1;
            if (hh < 0 || hh >= H_) continue;
            float a0 = (w - 1 >= 0) ? qb[hh * W_ + w - 1] : 0.f;
            float a1 = qb[hh * W_ + w];
            float a2 = (w + 1 < W_) ? qb[hh * W_ + w + 1] : 0.f;
            const float* wp0 = lawp + (ci * 9 + kh * 3) * RCH;   // uniform -> s_load
#pragma unroll
            for (int co = 0; co < RCH; co++)
                acc[co] += a0 * wp0[co] + a1 * wp0[RCH + co] + a2 * wp0[2 * RCH + co];
        }
    }
#pragma unroll
    for (int co = 0; co < RCH; co++) lraw[((size_t)b * RCH + co) * HW + p] = acc[co];
}

// ---------- 8. fused: GN(lraw)+elu -> attn MLP -> sigmoid; warp km; vol ----------
__global__ __launch_bounds__(256) void k_vol(const float* __restrict__ lraw,
    const float* __restrict__ stats, const float* __restrict__ lg, const float* __restrict__ lb,
    const float* __restrict__ gbias, const float* __restrict__ afw1,
    const float* __restrict__ afw2, const float* __restrict__ afb2,
    const float* __restrict__ km, const float* __restrict__ directs, float* __restrict__ vol)
{
    __shared__ float w1[RCH * 2 * RCH];   // 512
    __shared__ float w2[D_ * RCH];        // 768
    __shared__ float b2[D_];
    for (int i = threadIdx.x; i < RCH * 2 * RCH; i += 256) w1[i] = afw1[i];
    for (int i = threadIdx.x; i < D_ * RCH; i += 256) w2[i] = afw2[i];
    if (threadIdx.x < D_) b2[threadIdx.x] = afb2[threadIdx.x];
    __syncthreads();
    int idx = blockIdx.x * 256 + threadIdx.x;      // B_*HW
    int b = idx / HW, p = idx - b * HW;
    int h = p / W_, w = p - h * W_;
    float lf[RCH];
#pragma unroll
    for (int rc = 0; rc < RCH; rc++) {
        int g = rc >> 1;
        float m = stats[(b * NG + g) * 2], is = stats[(b * NG + g) * 2 + 1];
        lf[rc] = elu1((lraw[((size_t)b * RCH + rc) * HW + p] - m) * is * lg[rc] + lb[rc]);
    }
    float hid[RCH];
#pragma unroll
    for (int o = 0; o < RCH; o++) {
        float a = gbias[b * RCH + o];
#pragma unroll
        for (int i = 0; i < RCH; i++) a += w1[o * 2 * RCH + RCH + i] * lf[i];
        hid[o] = elu1(a);
    }
    const float* kmrow = km + (size_t)b * HW + h * W_;
    float dir = directs[b];
    for (int d = 0; d < D_; d++) {
        float a = b2[d];
#pragma unroll
        for (int o = 0; o < RCH; o++) a += w2[d * RCH + o] * hid[o];
        float s = sigm(a);
        float shift = ((float)d / 160.f) * dir * (float)(W_ - 1);
        float pos = (float)w + shift;
        float x0 = floorf(pos);
        float f = pos - x0;
        float c0 = fminf(fmaxf(x0, 0.f), (float)(W_ - 1));
        float c1 = fminf(fmaxf(x0 + 1.f, 0.f), (float)(W_ - 1));
        int i0 = (int)c0, i1 = (int)c1;
        float wv = kmrow[i0] * (1.f - f) + kmrow[i1] * f;
        vol[((size_t)(b * D_ + d)) * HW + p] = wv * s;
    }
}

// ---------- 9. depthwise 3x3 + elu, 4 px/thread ----------
__global__ __launch_bounds__(256) void k_dw(const float* __restrict__ vol,
    const float* __restrict__ wgt, const float* __restrict__ bias, float* __restrict__ dwout)
{
    int idx = blockIdx.x * 256 + threadIdx.x;      // B_*D_*HW/4
    int p4 = idx % (HW / 4);
    int d  = (idx / (HW / 4)) % D_;
    int b  = idx / (D_ * HW / 4);
    int h = p4 / (W_ / 4), w = (p4 % (W_ / 4)) * 4;
    const float* vb = vol + ((size_t)(b * D_ + d)) * HW;
    float wz[9];
#pragma unroll
    for (int i = 0; i < 9; i++) wz[i] = wgt[d * 9 + i];
    float bv = bias[d];
    float acc[4] = {bv, bv, bv, bv};
#pragma unroll
    for (int r = 0; r < 3; r++) {
        int hh = h + r - 1;
        if (hh < 0 || hh >= H_) continue;
        const float* row = vb + hh * W_;
        float4 c = *(const float4*)(row + w);
        float in6[6];
        in6[0] = (w > 0) ? row[w - 1] : 0.f;
        in6[1] = c.x; in6[2] = c.y; in6[3] = c.z; in6[4] = c.w;
        in6[5] = (w + 4 < W_) ? row[w + 4] : 0.f;
#pragma unroll
        for (int j = 0; j < 4; j++)
            acc[j] += in6[j] * wz[r * 3] + in6[j + 1] * wz[r * 3 + 1] + in6[j + 2] * wz[r * 3 + 2];
    }
    float4 o;
    o.x = elu1(acc[0]); o.y = elu1(acc[1]); o.z = elu1(acc[2]); o.w = elu1(acc[3]);
    ((float4*)dwout)[idx] = o;
}

// ---------- 9b. prep: abf[b][h][322][120ci] bf16 — left channels (dw 0..31) + zero pad (dw 56..59) ----------
__global__ __launch_bounds__(256) void k_prep(const float* __restrict__ left, unsigned int* __restrict__ abf)
{
    int idx = blockIdx.x * 256 + threadIdx.x;      // B_*H_*APX = 123,648 exactly
    int px = idx % APX;
    int bh = idx / APX;
    int b = bh / H_, h = bh % H_;
    int w = px - 1;
    w = w < 0 ? -w : (w >= W_ ? 2 * W_ - 2 - w : w);
    const float* src = left + (size_t)b * C_ * HW + h * W_ + w;
    unsigned int* dst = abf + (size_t)idx * 60;
#pragma unroll
    for (int q4 = 0; q4 < 8; q4++) {
        u32x4 t;
#pragma unroll
        for (int z = 0; z < 4; z++) {
            int ci = (q4 * 4 + z) * 2;
            float f0 = src[(size_t)ci * HW];
            float f1 = src[(size_t)(ci + 1) * HW];
            t[z] = bf16rne(f0) | (bf16rne(f1) << 16);
        }
        *reinterpret_cast<u32x4*>(dst + q4 * 4) = t;
    }
    *reinterpret_cast<u32x4*>(dst + 56) = (u32x4){0u, 0u, 0u, 0u};
}

// ---------- 10. 1x1 48->48 + softmax -> norm_cost ; also writes abf dwords 32..55 ----------
__global__ __launch_bounds__(256) void k_rpw(const float* __restrict__ dwin,
    const float* __restrict__ wgt, const float* __restrict__ bias,
    float* __restrict__ ncost, unsigned int* __restrict__ abf)
{
    __shared__ float wr[D_ * D_];   // 2304
    __shared__ float bs[D_];
    for (int i = threadIdx.x; i < D_ * D_; i += 256) wr[i] = wgt[i];
    if (threadIdx.x < D_) bs[threadIdx.x] = bias[threadIdx.x];
    __syncthreads();
    int idx = blockIdx.x * 256 + threadIdx.x;      // B_*HW
    int b = idx / HW, p = idx - b * HW;
    int h = p / W_, w = p - h * W_;
    float v[D_];
#pragma unroll
    for (int i = 0; i < D_; i++) v[i] = dwin[((size_t)(b * D_ + i)) * HW + p];
    float cst[D_];
    float mx = -1e30f;
#pragma unroll
    for (int d = 0; d < D_; d++) {
        float a = bs[d];
        const float4* wrow = (const float4*)&wr[d * D_];
#pragma unroll
        for (int i4 = 0; i4 < D_ / 4; i4++) {
            float4 wv = wrow[i4];
            a += wv.x * v[i4 * 4 + 0] + wv.y * v[i4 * 4 + 1]
               + wv.z * v[i4 * 4 + 2] + wv.w * v[i4 * 4 + 3];
        }
        cst[d] = a; mx = fmaxf(mx, a);
    }
    float s = 0.f;
#pragma unroll
    for (int d = 0; d < D_; d++) { float e = __expf(cst[d] - mx); cst[d] = e; s += e; }
    float inv = 1.f / s;
#pragma unroll
    for (int d = 0; d < D_; d++) {
        cst[d] *= inv;
        ncost[((size_t)(b * D_ + d)) * HW + p] = cst[d];
    }
    u32x4 pk[6];
#pragma unroll
    for (int q4 = 0; q4 < 6; q4++)
#pragma unroll
        for (int z = 0; z < 4; z++) {
            int d = (q4 * 4 + z) * 2;
            pk[q4][z] = bf16rne(cst[d]) | (bf16rne(cst[d + 1]) << 16);
        }
    size_t bh322 = (size_t)(b * H_ + h) * APX;
    unsigned int* dst = abf + (bh322 + (w + 1)) * 60 + 32;
#pragma unroll
    for (int q4 = 0; q4 < 6; q4++) *reinterpret_cast<u32x4*>(dst + q4 * 4) = pk[q4];
    if (w == 1 || w == W_ - 2) {
        unsigned int* dst2 = abf + (bh322 + (w == 1 ? 0 : APX - 1)) * 60 + 32;
#pragma unroll
        for (int q4 = 0; q4 < 6; q4++) *reinterpret_cast<u32x4*>(dst2 + q4 * 4) = pk[q4];
    }
}

// ---------- 11a. weight prepack for MFMA fused conv ----------
__global__ __launch_bounds__(256) void k_wpack(const float* __restrict__ fw, unsigned short* __restrict__ wpack)
{
    int bi = blockIdx.x;           // 0..35
    int tap = bi >> 2, kblk = bi & 3;
    int kh = tap / 3, kw2 = tap % 3;
    int t = threadIdx.x;
    int ct = t >> 6, l = t & 63;
    int co = ct * 16 + (l & 15);
    int ci0 = kblk * 32 + ((l >> 4) & 3) * 8;
    unsigned short v[8];
#pragma unroll
    for (int j = 0; j < 8; j++) {
        int ci = ci0 + j;
        float f = (ci < 112) ? fw[((size_t)(co * 112 + ci)) * 9 + kh * 3 + kw2] : 0.f;
        v[j] = (unsigned short)bf16rne(f);
    }
    *reinterpret_cast<short8*>(wpack + ((size_t)bi * 256 + t) * 8) = *reinterpret_cast<short8*>(v);
}

// ---------- 11b. fused 3x3 conv 112->64, reflect pad, bf16 MFMA implicit GEMM ----------
static constexpr int LROWB  = 240;           // bytes per px (120 bf16)
static constexpr int LPLANB = 66 * LROWB;    // 15840 bytes per input row
__global__ __launch_bounds__(256, 1) void k_fused_mfma(
    const unsigned int* __restrict__ abf,
    const unsigned short* __restrict__ wpack, const float* __restrict__ fb,
    float* __restrict__ fused)
{
    __shared__ __align__(16) unsigned int Atile4[15844];   // 63376 B (incl 16B overread pad)
    int bb = blockIdx.z;
    int h0 = blockIdx.y * 2;
    int w0 = blockIdx.x * 64;
    int tid = threadIdx.x;
    int wid = tid >> 6;          // wave id
    int l   = tid & 63;

    {
        int hh = h0 - 1 + wid;
        hh = hh < 0 ? -hh : (hh >= H_ ? 2 * H_ - 2 - hh : hh);
        const char* gsrc = (const char*)(abf + ((size_t)(bb * H_ + hh) * APX + w0) * 60);
        char* lbase = (char*)Atile4 + wid * LPLANB;
#pragma unroll
        for (int i = 0; i < 15; i++)
            gload16(gsrc + (i * 64 + l) * 16, lbase + i * 1024);
        if (l < 30) gload16(gsrc + (960 + l) * 16, lbase + 15 * 1024);
    }
    __syncthreads();

    int row = wid >> 1;          // output row within block (0..1)
    int ch  = wid & 1;           // co half (0..1)
    int li = l & 15, lg = l >> 4;

    const short8* __restrict__ wp8 = reinterpret_cast<const short8*>(wpack);

    f32x4 acc[4][2];
    float bv0 = fb[(ch * 2 + 0) * 16 + li];
    float bv1 = fb[(ch * 2 + 1) * 16 + li];
#pragma unroll
    for (int pt = 0; pt < 4; pt++) {
        acc[pt][0] = (f32x4){bv0, bv0, bv0, bv0};
        acc[pt][1] = (f32x4){bv1, bv1, bv1, bv1};
    }

    const char* Abase = (const char*)Atile4;
#pragma unroll
    for (int kh = 0; kh < 3; kh++) {
#pragma unroll
        for (int kw2 = 0; kw2 < 3; kw2++) {
#pragma unroll
            for (int kblk = 0; kblk < 4; kblk++) {
                int step = (kh * 3 + kw2) * 4 + kblk;
                short8 b0 = wp8[step * 256 + (ch * 2 + 0) * 64 + l];
                short8 b1 = wp8[step * 256 + (ch * 2 + 1) * 64 + l];
                int rbase = (row + kh) * LPLANB + kblk * 64 + lg * 16 + (kw2 + li) * LROWB;
#pragma unroll
                for (int pt = 0; pt < 4; pt++) {
                    short8 a = *reinterpret_cast<const short8*>(Abase + rbase + pt * (16 * LROWB));
                    acc[pt][0] = __builtin_amdgcn_mfma_f32_16x16x32_bf16(a, b0, acc[pt][0], 0, 0, 0);
                    acc[pt][1] = __builtin_amdgcn_mfma_f32_16x16x32_bf16(a, b1, acc[pt][1], 0, 0, 0);
                }
            }
        }
    }

    int h = h0 + row;
#pragma unroll
    for (int j = 0; j < 2; j++) {
        int co = (ch * 2 + j) * 16 + li;
        float* ob = fused + ((size_t)(bb * C_ + co) * H_ + h) * W_ + w0 + lg * 4;
#pragma unroll
        for (int pt = 0; pt < 4; pt++) {
            *reinterpret_cast<f32x4*>(ob + pt * 16) = acc[pt][j];
        }
    }
}

// ---------- 12. SE MLP ----------
__global__ __launch_bounds__(256) void k_se(const float* __restrict__ ymean,
    const float* __restrict__ w1, const float* __restrict__ w2, float* __restrict__ scale)
{
    __shared__ float h4[B_ * 4];
    int t = threadIdx.x;
    if (t < B_ * 4) {
        int b = t >> 2, o = t & 3;
        float a = 0.f;
        for (int c = 0; c < C_; c++) a += w1[o * C_ + c] * ymean[b * C_ + c];
        h4[b * 4 + o] = fmaxf(a, 0.f);
    }
    __syncthreads();
    {
        int b = t >> 6, c = t & 63;
        float a = 0.f;
        for (int o = 0; o < 4; o++) a += w2[c * 4 + o] * h4[b * 4 + o];
        scale[t] = sigm(a);
    }
}

// ---------- 13. final: x = elu(fused * scale), float4 ----------
__global__ __launch_bounds__(256) void k_final(const float* __restrict__ fused,
    const float* __restrict__ scale, float* __restrict__ out)
{
    int idx4 = blockIdx.x * 256 + threadIdx.x;     // B_*C_*HW/4
    int bc = idx4 / (HW / 4);
    float sc = scale[bc];
    float4 v = ((const float4*)fused)[idx4];
    v.x = elu1(v.x * sc); v.y = elu1(v.y * sc);
    v.z = elu1(v.z * sc); v.w = elu1(v.w * sc);
    ((float4*)out)[idx4] = v;
}

extern "C" void kernel_launch(void* const* d_in, const int* in_sizes, int n_in,
                              void* d_out, int out_size, void* d_ws, size_t ws_size,
                              hipStream_t stream)
{
    const float* left   = (const float*)d_in[0];
    const float* right  = (const float*)d_in[1];
    const float* directs= (const float*)d_in[2];
    const float* qw     = (const float*)d_in[3];
    const float* q_g    = (const float*)d_in[4];
    const float* q_b    = (const float*)d_in[5];
    const float* kw     = (const float*)d_in[6];
    const float* k_g    = (const float*)d_in[7];
    const float* k_b    = (const float*)d_in[8];
    const float* gaw1   = (const float*)d_in[9];
    const float* gab1   = (const float*)d_in[10];
    const float* gaw2   = (const float*)d_in[11];
    const float* gab2   = (const float*)d_in[12];
    const float* law    = (const float*)d_in[13];
    const float* lab    = (const float*)d_in[14];
    const float* lag    = (const float*)d_in[15];
    const float* labb   = (const float*)d_in[16];
    const float* afw1   = (const float*)d_in[17];
    const float* afb1   = (const float*)d_in[18];
    const float* afw2   = (const float*)d_in[19];
    const float* afb2   = (const float*)d_in[20];
    const float* rdww   = (const float*)d_in[21];
    const float* rdwb   = (const float*)d_in[22];
    const float* rpww   = (const float*)d_in[23];
    const float* rpwb   = (const float*)d_in[24];
    const float* fuw    = (const float*)d_in[25];
    const float* fub    = (const float*)d_in[26];
    const float* sew1   = (const float*)d_in[27];
    const float* sew2   = (const float*)d_in[28];

    // workspace layout (floats). Peak 15,852,544 floats = 63.4 MB (same proven footprint).
    float* ws    = (float*)d_ws;
    float* qraw  = ws + 0;
    float* kraw  = ws + 1966080;
    float* km    = ws + 3932160;
    float* vol   = ws + 4055040;
    float* dwb   = ws + 9953280;          // ends 15,851,520
    float* smal  = ws + 15851520;         // 1024 floats
    unsigned int* abf = (unsigned int*)(ws + 0);       // B*H*322*60 dwords = 7,418,880 floats
    float* fused = ws + 7418880;          // 7,864,320 -> ends 15,283,200
    float* lraw  = kraw;
    unsigned short* wpack = (unsigned short*)(ws + 15811584);  // 73,728 bf16, ends 15,848,448

    // repacked conv weights carved from dwb start (dead by the time k_dw writes dwb)
    float* qwp   = dwb + 0;               // 1024
    float* kwp   = dwb + 1024;            // 1024
    float* lawp  = dwb + 2048;            // 2304 (ends dwb+4352)

    float* stQ   = smal + 0;
    float* stK   = smal + 64;
    float* stL   = smal + 128;
    float* gp    = smal + 192;
    float* gbias = smal + 256;
    float* ymean = smal + 320;
    float* scal  = smal + 576;

    float* xout  = (float*)d_out;            // 7,864,320
    float* ncost = xout + 7864320;           // 5,898,240

    k_wrepack<<<1, 256, 0, stream>>>(qw, kw, law, qwp, kwp, lawp);
    k_conv_qk<<<480, 256, 0, stream>>>(left, right, qwp, kwp, qraw, kraw);
    k_gn_stats<<<32, 256, 0, stream>>>(qraw, stQ);
    k_gn_stats<<<32, 256, 0, stream>>>(kraw, stK);
    k_gn_apply<<<1920, 256, 0, stream>>>(qraw, stQ, q_g, q_b);
    k_km<<<480, 256, 0, stream>>>(kraw, stK, k_g, k_b, km);
    k_rowmean<<<64, 256, 0, stream>>>(qraw, gp);
    k_gfeat<<<1, 64, 0, stream>>>(gp, gaw1, gab1, gaw2, gab2, afw1, afb1, gbias);
    k_conv_la<<<480, 256, 0, stream>>>(qraw, lawp, lab, lraw);
    k_gn_stats<<<32, 256, 0, stream>>>(lraw, stL);
    k_vol<<<480, 256, 0, stream>>>(lraw, stL, lag, labb, gbias, afw1, afw2, afb2, km, directs, vol);
    k_dw<<<5760, 256, 0, stream>>>(vol, rdww, rdwb, dwb);
    k_prep<<<483, 256, 0, stream>>>(left, abf);
    k_rpw<<<480, 256, 0, stream>>>(dwb, rpww, rpwb, ncost, abf);
    k_wpack<<<36, 256, 0, stream>>>(fuw, wpack);
    k_fused_mfma<<<dim3(5, 48, 4), 256, 0, stream>>>(abf, wpack, fub, fused);
    k_rowmean<<<256, 256, 0, stream>>>(fused, ymean);
    k_se<<<1, 256, 0, stream>>>(ymean, sew1, sew2, scal);
    k_final<<<7680, 256, 0, stream>>>(fused, scal, xout);
}